// Round 9
// baseline (819.990 us; speedup 1.0000x reference)
//
#include <hip/hip_runtime.h>

typedef __attribute__((ext_vector_type(8))) short bf16x8;
typedef __attribute__((ext_vector_type(4))) float f32x4;
typedef unsigned short u16;

#define MFMA(a,b,c) __builtin_amdgcn_mfma_f32_16x16x32_bf16((a),(b),(c),0,0,0)

__device__ __forceinline__ short f2bf(float f){
  union { float f; unsigned u; } v; v.f = f;
  unsigned r = v.u + 0x7FFFu + ((v.u >> 16) & 1u);
  return (short)(r >> 16);
}
__device__ __forceinline__ float bf2f(short s){
  union { unsigned u; float f; } v; v.u = ((unsigned)(unsigned short)s) << 16; return v.f;
}
__device__ __forceinline__ bf16x8 pack8(f32x4 x, f32x4 y){
  bf16x8 r;
  r[0]=f2bf(x[0]); r[1]=f2bf(x[1]); r[2]=f2bf(x[2]); r[3]=f2bf(x[3]);
  r[4]=f2bf(y[0]); r[5]=f2bf(y[1]); r[6]=f2bf(y[2]); r[7]=f2bf(y[3]);
  return r;
}
// hole swizzle: physical 16B-chunk index for logical chunk c of row
__device__ __forceinline__ int pch(int c, int row){ return (c & ~7) | ((c & 7) ^ (row & 7)); }

__device__ __forceinline__ void gload16(void* lp, const void* gp){
  __builtin_amdgcn_global_load_lds((const __attribute__((address_space(1))) unsigned*)gp,
                                   (__attribute__((address_space(3))) unsigned*)lp, 16, 0, 0);
}
// stage 16KB weight half-block: 128 rows x 8 chunks (k-half of a [128][128] image block)
__device__ __forceinline__ void stWB(short* buf, const short* img, int half, int w, int lane){
  const char* gp = (const char*)img;
  #pragma unroll
  for (int it=0; it<4; ++it){
    int id = it*256 + w*64 + lane; int r = id>>3, c = id&7;
    gload16((char*)buf + it*4096 + w*1024, gp + r*256 + half*128 + c*16);
  }
}
// stage 16KB A-tile: 128 rows x 8 chunks from pre-swizzled hole (rowb pre-offset to hole)
__device__ __forceinline__ void stA128(short* buf, const u16* rowb, int kstep, int w, int lane){
  #pragma unroll
  for (int it=0; it<4; ++it){
    int id = it*256 + w*64 + lane; int r = id>>3, c = id&7;
    gload16((char*)buf + it*4096 + w*1024, rowb + (size_t)r*1536 + (kstep*8 + c)*8);
  }
}

// ---------------- prep kernels ----------------
// gate weights only (Wg1 top 2/3), 72 blocks
__global__ void prep_w(const float* __restrict__ Wg1, short* __restrict__ WaI, short* __restrict__ WbI){
  __shared__ short lt[128][136];
  int blk = blockIdx.x;            // 72 = 2 mats * 6 kt * 6 jt
  int mat = blk / 36, t = blk % 36, kt = t / 6, jt = t % 6;
  const float* src = (mat==0)? Wg1 : (Wg1 + (size_t)768*768);
  short* dst = (mat==0)? WaI : WbI;
  int tid = threadIdx.x;
  #pragma unroll
  for (int it=0; it<16; ++it){
    int kl = it*8 + (tid>>5);
    int jl = (tid&31)*4;
    f32x4 v = *(const f32x4*)&src[(size_t)(kt*128+kl)*768 + jt*128 + jl];
    lt[jl+0][kl]=f2bf(v[0]); lt[jl+1][kl]=f2bf(v[1]);
    lt[jl+2][kl]=f2bf(v[2]); lt[jl+3][kl]=f2bf(v[3]);
  }
  __syncthreads();
  size_t base = (size_t)(jt*6 + kt)*16384;
  #pragma unroll
  for (int cc=0; cc<8; ++cc){
    int ci = cc*256 + tid;
    int jl = ci >> 4, sc = ci & 15;
    int kkb = ((sc ^ (jl & 7)) << 3);
    bf16x8 v = *(const bf16x8*)&lt[jl][kkb];
    *(bf16x8*)&dst[base + (size_t)jl*128 + sc*8] = v;
  }
}

// 96 blocks = 12 j-tiles(64 cols) x 8 concept-groups(8 concepts)
__global__ __launch_bounds__(256) void prep_kv(const float* __restrict__ ce,
                        const float* __restrict__ Wk, const float* __restrict__ bk,
                        const float* __restrict__ Wv, const float* __restrict__ bv,
                        short* __restrict__ Kc, short* __restrict__ VT){
  __shared__ float sh[8][768];
  int jt = blockIdx.x / 8, cg = blockIdx.x % 8;
  int tid = threadIdx.x;
  int j = jt*64 + (tid & 63);
  int cl = tid >> 6;
  for (int i = tid; i < 8*768; i += 256){
    int c2 = i / 768; int h = i - c2*768;
    sh[c2][h] = ce[(size_t)(cg*8+c2)*768 + h];
  }
  __syncthreads();
  float aK0=0.f, aV0=0.f, aK1=0.f, aV1=0.f;
  #pragma unroll 4
  for (int h=0; h<768; ++h){
    float wk = Wk[(size_t)h*768 + j];
    float wv = Wv[(size_t)h*768 + j];
    float x0 = sh[cl*2][h], x1 = sh[cl*2+1][h];
    aK0 += x0*wk; aV0 += x0*wv;
    aK1 += x1*wk; aV1 += x1*wv;
  }
  float bkj = bk[j], bvj = bv[j];
  int c0 = cg*8 + cl*2;
  Kc[(size_t)c0*768 + j]     = f2bf(aK0 + bkj);
  Kc[(size_t)(c0+1)*768 + j] = f2bf(aK1 + bkj);
  VT[(size_t)j*64 + c0]      = f2bf(aV0 + bvj);
  VT[(size_t)j*64 + c0+1]    = f2bf(aV1 + bvj);
}

// 17 blocks: 0-11 wg1c; 12-14 cp; 15-16 sbias = (bq . K_head)/sqrt(96)
__global__ void prep_misc(const float* __restrict__ Wg1, const float* __restrict__ ce,
                          const float* __restrict__ bq, const short* __restrict__ Kc,
                          float* __restrict__ wg1c, float* __restrict__ cp,
                          float* __restrict__ sbias){
  __shared__ float red[4][64];
  int b = blockIdx.x, tid = threadIdx.x;
  if (b < 12){
    int j = b*64 + (tid & 63);
    int kq = tid >> 6;
    float s = 0.f;
    for (int r=0; r<192; ++r)
      s += Wg1[(size_t)(1536 + kq*192 + r)*768 + j];
    red[kq][tid&63] = s;
    __syncthreads();
    if (tid < 64) wg1c[b*64+tid] = red[0][tid]+red[1][tid]+red[2][tid]+red[3][tid];
  } else if (b < 15){
    int h = (b-12)*256 + tid;
    float s = 0.f;
    #pragma unroll
    for (int c2=0; c2<64; ++c2) s += ce[(size_t)c2*768 + h];
    cp[h] = s * (1.f/64.f);
  } else {
    int hc = (b-15)*256 + tid;
    int h = hc >> 6, c = hc & 63;
    float s = 0.f;
    #pragma unroll
    for (int j=0; j<96; ++j)
      s += bq[h*96+j] * bf2f(Kc[(size_t)c*768 + h*96 + j]);
    sbias[hc] = s * 0.10206207262f;
  }
}

// Weff image: Weff[k=d][n=hc] = sum_j Wq[d][h*96+j]*K[c][h*96+j] * invsqrt96
// 24 blocks = nb(0..3) x kt(0..5); image block (nb*6+kt): [128 n][128 k]
__global__ __launch_bounds__(256) void prep_eff(const float* __restrict__ Wq,
                        const short* __restrict__ Kc, short* __restrict__ WeffI){
  __shared__ short Kst[2][64][96];
  int nb = blockIdx.x/6, kt = blockIdx.x%6, tid = threadIdx.x;
  int h0 = nb*2;
  for (int i=tid; i<12288; i+=256){
    int hh = i/6144, c = (i/96)%64, j = i%96;
    Kst[hh][c][j] = Kc[(size_t)c*768 + (size_t)(h0+hh)*96 + j];
  }
  __syncthreads();
  int hcl = tid & 127, hh = hcl>>6, c = hcl&63;
  int dbase = (tid>>7)*64;
  size_t base = (size_t)(nb*6+kt)*16384;
  #pragma unroll 1
  for (int i=0;i<64;++i){
    int d = dbase + i;
    float s = 0.f;
    #pragma unroll 8
    for (int j=0;j<96;++j)
      s += Wq[(size_t)(kt*128+d)*768 + (size_t)(h0+hh)*96 + j] * bf2f(Kst[hh][c][j]);
    WeffI[base + (size_t)hcl*128 + (((d>>3)^(hcl&7))<<3) + (d&7)] = f2bf(s * 0.10206207262f);
  }
}

// VWo image: VWo[k=hc][n=d] = sum_j V[c][h*96+j]*Wo[h*96+j][d]
// 24 blocks = nb(0..5) x kt(0..3); image block (nb*4+kt): [128 n=d][128 k=hc]
__global__ __launch_bounds__(256) void prep_vwo(const float* __restrict__ Wo,
                        const short* __restrict__ VT, short* __restrict__ VWoI){
  __shared__ short Vst[2][64][96];
  int nb = blockIdx.x/4, kt = blockIdx.x%4, tid = threadIdx.x;
  int h0 = kt*2;
  for (int i=tid; i<12288; i+=256){
    int hh = i/6144, c = (i/96)%64, j = i%96;
    Vst[hh][c][j] = VT[((size_t)(h0+hh)*96 + j)*64 + c];
  }
  __syncthreads();
  int dl = tid & 127;
  int hcb = (tid>>7)*64;
  size_t base = (size_t)(nb*4+kt)*16384;
  #pragma unroll 1
  for (int i=0;i<64;++i){
    int hcl = hcb + i;
    int hh = hcl>>6, c = hcl&63;
    float s = 0.f;
    #pragma unroll 8
    for (int j=0;j<96;++j)
      s += bf2f(Vst[hh][c][j]) * Wo[((size_t)(h0+hh)*96 + j)*768 + nb*128 + dl];
    VWoI[base + (size_t)dl*128 + (((hcl>>3)^(dl&7))<<3) + (hcl&7)] = f2bf(s);
  }
}

// hs f32 -> bf16 pre-swizzled hole1 + partial column sums. 512 blocks x 384 thr.
__global__ __launch_bounds__(384) void prep_hs(const float* __restrict__ hs,
                                               float* __restrict__ outp, float* __restrict__ tpp){
  __shared__ float csum[4][768];
  int tid = threadIdx.x;
  int c = tid % 96, rg = tid / 96;
  size_t r0 = (size_t)blockIdx.x * 128;
  u16* holes = (u16*)outp;
  float s[8];
  #pragma unroll
  for (int j=0;j<8;++j) s[j]=0.f;
  #pragma unroll 4
  for (int i=0; i<32; ++i){
    size_t row = r0 + rg*32 + i;
    const float* p = hs + row*768 + c*8;
    f32x4 x = __builtin_nontemporal_load((const f32x4*)p);
    f32x4 y = __builtin_nontemporal_load((const f32x4*)(p+4));
    *(bf16x8*)&holes[row*1536 + pch(c,(int)row)*8] = pack8(x,y);
    #pragma unroll
    for (int j=0;j<4;++j){ s[j]+=x[j]; s[4+j]+=y[j]; }
  }
  #pragma unroll
  for (int j=0;j<8;++j) csum[rg][c*8+j] = s[j];
  __syncthreads();
  for (int cc=tid; cc<768; cc+=384)
    tpp[(size_t)blockIdx.x*768 + cc] = csum[0][cc]+csum[1][cc]+csum[2][cc]+csum[3][cc];
}

__global__ void pool2(const float* __restrict__ tpp, float* __restrict__ tp){
  int b = blockIdx.x / 3, hc = blockIdx.x % 3;
  int h = hc*256 + threadIdx.x;
  float s = 0.f;
  #pragma unroll
  for (int k=0; k<32; ++k) s += tpp[((size_t)b*32 + k)*768 + h];
  tp[(size_t)b*768 + h] = s * (1.f/4096.f);
}
__global__ void pool3(const float* __restrict__ tp, const float* __restrict__ cp, float* __restrict__ rel){
  int b = blockIdx.x;
  float a=0.f, n1=0.f, n2=0.f;
  for (int h = threadIdx.x; h < 768; h += 256){
    float t = tp[(size_t)b*768 + h], c = cp[h];
    a += t*c; n1 += t*t; n2 += c*c;
  }
  #pragma unroll
  for (int m=1; m<64; m<<=1){ a+=__shfl_xor(a,m); n1+=__shfl_xor(n1,m); n2+=__shfl_xor(n2,m); }
  __shared__ float r3[3][4];
  int w = threadIdx.x >> 6;
  if ((threadIdx.x & 63) == 0){ r3[0][w]=a; r3[1][w]=n1; r3[2][w]=n2; }
  __syncthreads();
  if (threadIdx.x == 0){
    float A = r3[0][0]+r3[0][1]+r3[0][2]+r3[0][3];
    float N1= r3[1][0]+r3[1][1]+r3[1][2]+r3[1][3];
    float N2= r3[2][0]+r3[2][1]+r3[2][2]+r3[2][3];
    rel[b] = A / (fmaxf(sqrtf(N1),1e-8f) * fmaxf(sqrtf(N2),1e-8f));
  }
}

// ---------------- gs: S = hs @ Weff + sbias -> hole2[0,512) bf16 ----------------
__global__ __launch_bounds__(256) void gs(const short* __restrict__ WeffI,
                                          const float* __restrict__ sbias, float* outp){
  __shared__ short A0[8192], A1[8192], B0[8192], B1[8192];
  const int tid = threadIdx.x, lane = tid & 63, w = tid >> 6;
  const int l15 = lane & 15, g = lane >> 4;
  const int bid = blockIdx.x;
  const int nb = (bid >> 3) & 3, mt = (bid/32)*8 + (bid & 7);
  const int wm = w & 1, wn = w >> 1;
  const size_t t0 = (size_t)mt*128;
  u16* holes = (u16*)outp;
  const u16* Arow = holes + t0*1536;
  const short* Wimg = WeffI + (size_t)nb*6*16384;
  f32x4 acc[4][4];
  #pragma unroll
  for (int i=0;i<4;++i)
    #pragma unroll
    for (int j=0;j<4;++j) acc[i][j] = (f32x4){0.f,0.f,0.f,0.f};
  stA128(A0, Arow, 0, w, lane);
  stWB(B0, Wimg, 0, w, lane);
  __syncthreads();
  #pragma unroll
  for (int ks2=0; ks2<12; ++ks2){
    const short* Ac = (ks2&1)? A1 : A0;
    const short* Bc = (ks2&1)? B1 : B0;
    short* An = (ks2&1)? A0 : A1;
    short* Bn = (ks2&1)? B0 : B1;
    if (ks2<11){
      stA128(An, Arow, ks2+1, w, lane);
      stWB(Bn, Wimg + (size_t)(((ks2+1)>>1))*16384, (ks2+1)&1, w, lane);
    }
    #pragma unroll
    for (int ks=0; ks<2; ++ks){
      bf16x8 a[4], b[4];
      #pragma unroll
      for (int mf=0; mf<4; ++mf){ int r = wm*64+mf*16+l15; a[mf] = *(const bf16x8*)&Ac[r*64 + (((ks*4+g)^(r&7))<<3)]; }
      #pragma unroll
      for (int nf=0; nf<4; ++nf){ int r = wn*64+nf*16+l15; b[nf] = *(const bf16x8*)&Bc[r*64 + (((ks*4+g)^(r&7))<<3)]; }
      #pragma unroll
      for (int mf=0; mf<4; ++mf)
        #pragma unroll
        for (int nf=0; nf<4; ++nf)
          acc[mf][nf] = MFMA(a[mf], b[nf], acc[mf][nf]);
    }
    __syncthreads();
  }
  #pragma unroll
  for (int mf=0; mf<4; ++mf)
    #pragma unroll
    for (int nf=0; nf<4; ++nf)
      #pragma unroll
      for (int r=0; r<4; ++r){
        int grow = wm*64 + mf*16 + g*4 + r;
        int col = nb*128 + wn*64 + nf*16 + l15;
        float v = acc[mf][nf][r] + sbias[col];
        holes[(t0+grow)*1536 + 768 + pch(col>>3, grow)*8 + (col&7)] = (u16)f2bf(v);
      }
}

// ---------------- sm: per-row softmax per head (64-col groups) in place + attn_avg ----------------
__global__ __launch_bounds__(256) void sm(float* outp){
  const int tid = threadIdx.x, lane = tid & 63, w = tid >> 6;
  u16* holes = (u16*)outp;
  #pragma unroll 1
  for (int i=0; i<8; ++i){
    int row = i*8192 + blockIdx.x*4 + w;
    u16* p = &holes[(size_t)row*1536 + 768 + pch(lane,row)*8];
    bf16x8 v = *(const bf16x8*)p;
    float x[8];
    #pragma unroll
    for (int j=0;j<8;++j) x[j] = bf2f(v[j]);
    float m = x[0];
    #pragma unroll
    for (int j=1;j<8;++j) m = fmaxf(m, x[j]);
    m = fmaxf(m, __shfl_xor(m,1)); m = fmaxf(m, __shfl_xor(m,2)); m = fmaxf(m, __shfl_xor(m,4));
    float s = 0.f;
    #pragma unroll
    for (int j=0;j<8;++j){ x[j] = __expf(x[j]-m); s += x[j]; }
    s += __shfl_xor(s,1); s += __shfl_xor(s,2); s += __shfl_xor(s,4);
    float inv = 1.f/s;
    bf16x8 o;
    #pragma unroll
    for (int j=0;j<8;++j){ x[j] *= inv; o[j] = f2bf(x[j]); }
    *(bf16x8*)p = o;
    // attn_avg: sum over 8 heads (lanes differing in bits 3-5), then /8
    #pragma unroll
    for (int j=0;j<8;++j){
      x[j] += __shfl_xor(x[j],8); x[j] += __shfl_xor(x[j],16); x[j] += __shfl_xor(x[j],32);
      x[j] *= 0.125f;
    }
    if (lane < 8){
      f32x4 o0, o1;
      #pragma unroll
      for (int j=0;j<4;++j){ o0[j]=x[j]; o1[j]=x[4+j]; }
      float* ap = &outp[(size_t)50331648 + (size_t)row*64 + lane*8];
      __builtin_nontemporal_store(o0, (f32x4*)ap);
      __builtin_nontemporal_store(o1, (f32x4*)(ap+4));
    }
  }
}

// ---------------- gvwo: ctxo = attn @ VWo + bo -> hole2[0,768) (attn reg-staged first) ----------------
__global__ __launch_bounds__(256) void gvwo(const short* __restrict__ VWoI,
                                            const float* __restrict__ bo, float* outp){
  __shared__ short B0[8192], B1[8192];
  const int tid = threadIdx.x, lane = tid & 63, w = tid >> 6;
  const int l15 = lane & 15, g = lane >> 4;
  const size_t t0 = (size_t)blockIdx.x * 64;
  const int arow = w*16 + l15;
  const int drow = w*16 + g*4;
  u16* holes = (u16*)outp;
  bf16x8 af[16];
  #pragma unroll
  for (int kk=0; kk<16; ++kk){
    int kc = kk*4 + g;
    af[kk] = *(const bf16x8*)&holes[(t0+arow)*1536 + 768 + pch(kc, arow)*8];
  }
  stWB(B0, VWoI, 0, w, lane);
  __syncthreads();
  #pragma unroll 1
  for (int nb=0; nb<6; ++nb){
    f32x4 acc[8];
    #pragma unroll
    for (int i=0;i<8;++i) acc[i]=(f32x4){0.f,0.f,0.f,0.f};
    #pragma unroll
    for (int ks2=0; ks2<8; ++ks2){
      const short* Bc = (ks2&1)? B1 : B0;
      short* Bn = (ks2&1)? B0 : B1;
      if (ks2<7)       stWB(Bn, VWoI + (size_t)(nb*4 + ((ks2+1)>>1))*16384, (ks2+1)&1, w, lane);
      else if (nb<5)   stWB(Bn, VWoI + (size_t)((nb+1)*4)*16384, 0, w, lane);
      #pragma unroll
      for (int ks=0; ks<2; ++ks){
        bf16x8 a = af[ks2*2 + ks];
        #pragma unroll
        for (int nf=0; nf<8; ++nf){
          int br = nf*16 + l15;
          bf16x8 b = *(const bf16x8*)&Bc[br*64 + (((ks*4+g)^(br&7))<<3)];
          acc[nf] = MFMA(a, b, acc[nf]);
        }
      }
      __syncthreads();
    }
    #pragma unroll
    for (int nf=0; nf<8; ++nf)
      #pragma unroll
      for (int r=0; r<4; ++r){
        int row = drow + r;
        int col = nb*128 + nf*16 + l15;
        float v = acc[nf][r] + bo[col];
        holes[(t0+row)*1536 + 768 + pch(col>>3, row)*8 + (col&7)] = (u16)f2bf(v);
      }
  }
}

// ---------------- gate_mm: per-(mt,nb) block, K=1536 (both passes), partial relu-dot -> gpart ----------------
__global__ __launch_bounds__(256) void gate_mm(const short* __restrict__ WaI,
    const short* __restrict__ WbI, const float* __restrict__ bg1,
    const float* __restrict__ wg1c, const float* __restrict__ Wg2,
    const float* __restrict__ rel, float* __restrict__ gpart, float* outp){
  __shared__ short A0[8192], A1[8192], B0[8192], B1[8192];
  const int tid = threadIdx.x, lane = tid & 63, w = tid >> 6;
  const int l15 = lane & 15, g = lane >> 4;
  const int bid = blockIdx.x;
  const int nb = (bid >> 3) % 6, mt = (bid/48)*8 + (bid & 7);
  const int wm = w & 1, wn = w >> 1;
  const size_t t0 = (size_t)mt*128;
  const float relb = rel[t0 >> 12];
  u16* holes = (u16*)outp;
  const u16* h1p = holes + t0*1536;
  const u16* h2p = h1p + 768;
  f32x4 acc[4][4];
  #pragma unroll
  for (int i=0;i<4;++i)
    #pragma unroll
    for (int j=0;j<4;++j) acc[i][j]=(f32x4){0.f,0.f,0.f,0.f};
  stA128(A0, h1p, 0, w, lane);
  stWB(B0, WaI + (size_t)nb*6*16384, 0, w, lane);
  __syncthreads();
  #pragma unroll
  for (int pass=0; pass<2; ++pass){
    const short* Wimg = (pass? WbI : WaI) + (size_t)nb*6*16384;
    const u16* Ap = pass ? h2p : h1p;
    #pragma unroll
    for (int ks2=0; ks2<12; ++ks2){
      const short* Ac = (ks2&1)? A1 : A0;
      const short* Bc = (ks2&1)? B1 : B0;
      short* An = (ks2&1)? A0 : A1;
      short* Bn = (ks2&1)? B0 : B1;
      if (ks2<11){
        stA128(An, Ap, ks2+1, w, lane);
        stWB(Bn, Wimg + (size_t)(((ks2+1)>>1))*16384, (ks2+1)&1, w, lane);
      } else if (pass==0){
        stA128(An, h2p, 0, w, lane);
        stWB(Bn, WbI + (size_t)nb*6*16384, 0, w, lane);
      }
      #pragma unroll
      for (int ks=0; ks<2; ++ks){
        bf16x8 a[4], b[4];
        #pragma unroll
        for (int mf=0; mf<4; ++mf){ int r = wm*64+mf*16+l15; a[mf] = *(const bf16x8*)&Ac[r*64 + (((ks*4+g)^(r&7))<<3)]; }
        #pragma unroll
        for (int nf=0; nf<4; ++nf){ int r = wn*64+nf*16+l15; b[nf] = *(const bf16x8*)&Bc[r*64 + (((ks*4+g)^(r&7))<<3)]; }
        #pragma unroll
        for (int mf=0; mf<4; ++mf)
          #pragma unroll
          for (int nf=0; nf<4; ++nf)
            acc[mf][nf] = MFMA(a[mf], b[nf], acc[mf][nf]);
      }
      __syncthreads();
    }
  }
  float gp[4][4];
  #pragma unroll
  for (int mf=0; mf<4; ++mf)
    #pragma unroll
    for (int r=0; r<4; ++r) gp[mf][r]=0.f;
  #pragma unroll
  for (int mf=0; mf<4; ++mf)
    #pragma unroll
    for (int nf=0; nf<4; ++nf)
      #pragma unroll
      for (int r=0; r<4; ++r){
        int col = nb*128 + wn*64 + nf*16 + l15;
        gp[mf][r] += fmaxf(acc[mf][nf][r] + bg1[col] + relb*wg1c[col], 0.f) * Wg2[col];
      }
  #pragma unroll
  for (int mf=0; mf<4; ++mf)
    #pragma unroll
    for (int r=0; r<4; ++r){
      float v = gp[mf][r];
      v += __shfl_xor(v,1); v += __shfl_xor(v,2); v += __shfl_xor(v,4); v += __shfl_xor(v,8);
      gp[mf][r] = v;
    }
  __syncthreads();
  float* gred = (float*)B0;
  if (l15 == 0)
    #pragma unroll
    for (int mf=0; mf<4; ++mf)
      #pragma unroll
      for (int r=0; r<4; ++r)
        gred[wn*128 + wm*64 + mf*16 + g*4 + r] = gp[mf][r];
  __syncthreads();
  if (tid < 128)
    gpart[(size_t)nb*65536 + t0 + tid] = gred[tid] + gred[128+tid];
}

// ---------------- lnk: out = LN(hs + sigmoid(sum gpart + bg2)*ctxo) ----------------
__global__ __launch_bounds__(256) void lnk(const float* __restrict__ gpart,
    const float* __restrict__ bg2, const float* __restrict__ lng,
    const float* __restrict__ lnb, float* outp){
  const int tid = threadIdx.x, lane = tid & 63, w = tid >> 6;
  u16* holes = (u16*)outp;
  const float bg2v = bg2[0];
  #pragma unroll 1
  for (int i=0; i<8; ++i){
    int row = blockIdx.x*32 + w*8 + i;
    float gsum = bg2v;
    #pragma unroll
    for (int nb2=0; nb2<6; ++nb2) gsum += gpart[(size_t)nb2*65536 + row];
    float gg = 1.f/(1.f + __expf(-gsum));
    int c1 = lane, c2 = 64 + (lane & 31);
    size_t rb = (size_t)row*1536;
    bf16x8 hv1 = *(const bf16x8*)&holes[rb + pch(c1,row)*8];
    bf16x8 ov1 = *(const bf16x8*)&holes[rb + 768 + pch(c1,row)*8];
    bf16x8 hv2 = *(const bf16x8*)&holes[rb + pch(c2,row)*8];
    bf16x8 ov2 = *(const bf16x8*)&holes[rb + 768 + pch(c2,row)*8];
    float x1[8], x2[8];
    float sum=0.f, sq=0.f;
    #pragma unroll
    for (int j=0;j<8;++j){ float x = bf2f(hv1[j]) + gg*bf2f(ov1[j]); x1[j]=x; sum+=x; sq+=x*x; }
    if (lane < 32){
      #pragma unroll
      for (int j=0;j<8;++j){ float x = bf2f(hv2[j]) + gg*bf2f(ov2[j]); x2[j]=x; sum+=x; sq+=x*x; }
    }
    #pragma unroll
    for (int m=1; m<64; m<<=1){ sum += __shfl_xor(sum,m); sq += __shfl_xor(sq,m); }
    float mu = sum * (1.f/768.f);
    float var = sq * (1.f/768.f) - mu*mu;
    float rs = rsqrtf(var + 1e-5f);
    {
      f32x4 ga = *(const f32x4*)&lng[c1*8], gb = *(const f32x4*)&lng[c1*8+4];
      f32x4 ba = *(const f32x4*)&lnb[c1*8], bb = *(const f32x4*)&lnb[c1*8+4];
      f32x4 o0, o1;
      #pragma unroll
      for (int j=0;j<4;++j){ o0[j] = (x1[j]-mu)*rs*ga[j]+ba[j]; o1[j] = (x1[4+j]-mu)*rs*gb[j]+bb[j]; }
      *(f32x4*)&outp[(size_t)row*768 + c1*8] = o0;
      *(f32x4*)&outp[(size_t)row*768 + c1*8 + 4] = o1;
    }
    if (lane < 32){
      f32x4 ga = *(const f32x4*)&lng[c2*8], gb = *(const f32x4*)&lng[c2*8+4];
      f32x4 ba = *(const f32x4*)&lnb[c2*8], bb = *(const f32x4*)&lnb[c2*8+4];
      f32x4 o0, o1;
      #pragma unroll
      for (int j=0;j<4;++j){ o0[j] = (x2[j]-mu)*rs*ga[j]+ba[j]; o1[j] = (x2[4+j]-mu)*rs*gb[j]+bb[j]; }
      *(f32x4*)&outp[(size_t)row*768 + c2*8] = o0;
      *(f32x4*)&outp[(size_t)row*768 + c2*8 + 4] = o1;
    }
  }
}

extern "C" void kernel_launch(void* const* d_in, const int* in_sizes, int n_in,
                              void* d_out, int out_size, void* d_ws, size_t ws_size,
                              hipStream_t stream) {
  (void)in_sizes; (void)n_in; (void)out_size; (void)ws_size;
  const float* hs  = (const float*)d_in[0];
  const float* ce  = (const float*)d_in[1];
  const float* Wq  = (const float*)d_in[2];
  const float* bq  = (const float*)d_in[3];
  const float* Wk  = (const float*)d_in[4];
  const float* bk  = (const float*)d_in[5];
  const float* Wv  = (const float*)d_in[6];
  const float* bv  = (const float*)d_in[7];
  const float* Wo  = (const float*)d_in[8];
  const float* bo  = (const float*)d_in[9];
  const float* Wg1 = (const float*)d_in[10];
  const float* bg1 = (const float*)d_in[11];
  const float* Wg2 = (const float*)d_in[12];
  const float* bg2 = (const float*)d_in[13];
  const float* lng = (const float*)d_in[14];
  const float* lnb = (const float*)d_in[15];
  char* ws = (char*)d_ws;
  short* WeffI = (short*)(ws + 0);         // 24 * 32KB = 768KB
  short* VWoI  = (short*)(ws + 1179648);   // 24 * 32KB = 768KB
  short* WaI   = (short*)(ws + 2359296);
  short* WbI   = (short*)(ws + 3538944);
  short* Kc    = (short*)(ws + 4718592);
  short* VT    = (short*)(ws + 4816896);
  float* wg1c  = (float*)(ws + 4915200);
  float* cp    = (float*)(ws + 4918272);
  float* tp    = (float*)(ws + 4921344);
  float* rel   = (float*)(ws + 4970496);
  float* tpp   = (float*)(ws + 4970752);   // 1.5MB
  float* gpart = (float*)(ws + 4970752);   // aliases tpp (dead by gate_mm)
  float* sbias = (float*)(ws + 6543616);   // 2KB
  float* outp  = (float*)d_out;

  prep_kv  <<<96,  256, 0, stream>>>(ce, Wk, bk, Wv, bv, Kc, VT);
  prep_w   <<<72,  256, 0, stream>>>(Wg1, WaI, WbI);
  prep_misc<<<17,  256, 0, stream>>>(Wg1, ce, bq, Kc, wg1c, cp, sbias);
  prep_eff <<<24,  256, 0, stream>>>(Wq, Kc, WeffI);
  prep_vwo <<<24,  256, 0, stream>>>(Wo, VT, VWoI);
  prep_hs  <<<512, 384, 0, stream>>>(hs, outp, tpp);
  pool2    <<<48,  256, 0, stream>>>(tpp, tp);
  pool3    <<<16,  256, 0, stream>>>(tp, cp, rel);
  gs       <<<2048,256, 0, stream>>>(WeffI, sbias, outp);
  sm       <<<2048,256, 0, stream>>>(outp);
  gvwo     <<<1024,256, 0, stream>>>(VWoI, bo, outp);
  gate_mm  <<<3072,256, 0, stream>>>(WaI, WbI, bg1, wg1c, Wg2, rel, gpart, outp);
  lnk      <<<2048,256, 0, stream>>>(gpart, bg2, lng, lnb, outp);
}

// Round 10
// 538.572 us; speedup vs baseline: 1.5225x; 1.5225x over previous
//
#include <hip/hip_runtime.h>

typedef __attribute__((ext_vector_type(8))) short bf16x8;
typedef __attribute__((ext_vector_type(4))) float f32x4;
typedef unsigned short u16;

#define MFMA(a,b,c) __builtin_amdgcn_mfma_f32_16x16x32_bf16((a),(b),(c),0,0,0)

__device__ __forceinline__ short f2bf(float f){
  union { float f; unsigned u; } v; v.f = f;
  unsigned r = v.u + 0x7FFFu + ((v.u >> 16) & 1u);
  return (short)(r >> 16);
}
__device__ __forceinline__ float bf2f(short s){
  union { unsigned u; float f; } v; v.u = ((unsigned)(unsigned short)s) << 16; return v.f;
}
__device__ __forceinline__ bf16x8 pack8(f32x4 x, f32x4 y){
  bf16x8 r;
  r[0]=f2bf(x[0]); r[1]=f2bf(x[1]); r[2]=f2bf(x[2]); r[3]=f2bf(x[3]);
  r[4]=f2bf(y[0]); r[5]=f2bf(y[1]); r[6]=f2bf(y[2]); r[7]=f2bf(y[3]);
  return r;
}
// hole swizzle: physical 16B-chunk index for logical chunk c of row
__device__ __forceinline__ int pch(int c, int row){ return (c & ~7) | ((c & 7) ^ (row & 7)); }

__device__ __forceinline__ void gload16(void* lp, const void* gp){
  __builtin_amdgcn_global_load_lds((const __attribute__((address_space(1))) unsigned*)gp,
                                   (__attribute__((address_space(3))) unsigned*)lp, 16, 0, 0);
}
// stage 16KB weight half-block: 128 rows x 8 chunks (k-half of a [128][128] image block)
__device__ __forceinline__ void stWB(short* buf, const short* img, int half, int w, int lane){
  const char* gp = (const char*)img;
  #pragma unroll
  for (int it=0; it<4; ++it){
    int id = it*256 + w*64 + lane; int r = id>>3, c = id&7;
    gload16((char*)buf + it*4096 + w*1024, gp + r*256 + half*128 + c*16);
  }
}
// stage 16KB A-tile: 128 rows x 8 chunks from pre-swizzled hole (rowb pre-offset to hole)
__device__ __forceinline__ void stA128(short* buf, const u16* rowb, int kstep, int w, int lane){
  #pragma unroll
  for (int it=0; it<4; ++it){
    int id = it*256 + w*64 + lane; int r = id>>3, c = id&7;
    gload16((char*)buf + it*4096 + w*1024, rowb + (size_t)r*1536 + (kstep*8 + c)*8);
  }
}

// ---------------- prep kernels ----------------
// gate weights only (Wg1 top 2/3), 72 blocks
__global__ void prep_w(const float* __restrict__ Wg1, short* __restrict__ WaI, short* __restrict__ WbI){
  __shared__ short lt[128][136];
  int blk = blockIdx.x;            // 72 = 2 mats * 6 kt * 6 jt
  int mat = blk / 36, t = blk % 36, kt = t / 6, jt = t % 6;
  const float* src = (mat==0)? Wg1 : (Wg1 + (size_t)768*768);
  short* dst = (mat==0)? WaI : WbI;
  int tid = threadIdx.x;
  #pragma unroll
  for (int it=0; it<16; ++it){
    int kl = it*8 + (tid>>5);
    int jl = (tid&31)*4;
    f32x4 v = *(const f32x4*)&src[(size_t)(kt*128+kl)*768 + jt*128 + jl];
    lt[jl+0][kl]=f2bf(v[0]); lt[jl+1][kl]=f2bf(v[1]);
    lt[jl+2][kl]=f2bf(v[2]); lt[jl+3][kl]=f2bf(v[3]);
  }
  __syncthreads();
  size_t base = (size_t)(jt*6 + kt)*16384;
  #pragma unroll
  for (int cc=0; cc<8; ++cc){
    int ci = cc*256 + tid;
    int jl = ci >> 4, sc = ci & 15;
    int kkb = ((sc ^ (jl & 7)) << 3);
    bf16x8 v = *(const bf16x8*)&lt[jl][kkb];
    *(bf16x8*)&dst[base + (size_t)jl*128 + sc*8] = v;
  }
}

// 96 blocks = 12 j-tiles(64 cols) x 8 concept-groups(8 concepts)
__global__ __launch_bounds__(256) void prep_kv(const float* __restrict__ ce,
                        const float* __restrict__ Wk, const float* __restrict__ bk,
                        const float* __restrict__ Wv, const float* __restrict__ bv,
                        short* __restrict__ Kc, short* __restrict__ VT){
  __shared__ float sh[8][768];
  int jt = blockIdx.x / 8, cg = blockIdx.x % 8;
  int tid = threadIdx.x;
  int j = jt*64 + (tid & 63);
  int cl = tid >> 6;
  for (int i = tid; i < 8*768; i += 256){
    int c2 = i / 768; int h = i - c2*768;
    sh[c2][h] = ce[(size_t)(cg*8+c2)*768 + h];
  }
  __syncthreads();
  float aK0=0.f, aV0=0.f, aK1=0.f, aV1=0.f;
  #pragma unroll 4
  for (int h=0; h<768; ++h){
    float wk = Wk[(size_t)h*768 + j];
    float wv = Wv[(size_t)h*768 + j];
    float x0 = sh[cl*2][h], x1 = sh[cl*2+1][h];
    aK0 += x0*wk; aV0 += x0*wv;
    aK1 += x1*wk; aV1 += x1*wv;
  }
  float bkj = bk[j], bvj = bv[j];
  int c0 = cg*8 + cl*2;
  Kc[(size_t)c0*768 + j]     = f2bf(aK0 + bkj);
  Kc[(size_t)(c0+1)*768 + j] = f2bf(aK1 + bkj);
  VT[(size_t)j*64 + c0]      = f2bf(aV0 + bvj);
  VT[(size_t)j*64 + c0+1]    = f2bf(aV1 + bvj);
}

// 17 blocks: 0-11 wg1c; 12-14 cp; 15-16 sbias = (bq . K_head)/sqrt(96)
__global__ void prep_misc(const float* __restrict__ Wg1, const float* __restrict__ ce,
                          const float* __restrict__ bq, const short* __restrict__ Kc,
                          float* __restrict__ wg1c, float* __restrict__ cp,
                          float* __restrict__ sbias){
  __shared__ float red[4][64];
  int b = blockIdx.x, tid = threadIdx.x;
  if (b < 12){
    int j = b*64 + (tid & 63);
    int kq = tid >> 6;
    float s = 0.f;
    for (int r=0; r<192; ++r)
      s += Wg1[(size_t)(1536 + kq*192 + r)*768 + j];
    red[kq][tid&63] = s;
    __syncthreads();
    if (tid < 64) wg1c[b*64+tid] = red[0][tid]+red[1][tid]+red[2][tid]+red[3][tid];
  } else if (b < 15){
    int h = (b-12)*256 + tid;
    float s = 0.f;
    #pragma unroll
    for (int c2=0; c2<64; ++c2) s += ce[(size_t)c2*768 + h];
    cp[h] = s * (1.f/64.f);
  } else {
    int hc = (b-15)*256 + tid;
    int h = hc >> 6, c = hc & 63;
    float s = 0.f;
    #pragma unroll
    for (int j=0; j<96; ++j)
      s += bq[h*96+j] * bf2f(Kc[(size_t)c*768 + h*96 + j]);
    sbias[hc] = s * 0.10206207262f;
  }
}

// Weff image via MFMA: 48 blocks = h(8) x kt(6). Out[c][d] = K_h(64x96) @ Wq_h^T; img[hc][d].
__global__ __launch_bounds__(256) void prep_eff(const float* __restrict__ Wq,
                        const short* __restrict__ Kc, short* __restrict__ WeffI){
  __shared__ short KA[64][104];    // A: [c][j]
  __shared__ short WB[128][104];   // B: [d][j]
  int h = blockIdx.x / 6, kt = blockIdx.x % 6, tid = threadIdx.x;
  const int lane = tid & 63, w = tid >> 6, l15 = lane & 15, g = lane >> 4;
  #pragma unroll
  for (int it=0; it<3; ++it){
    int i = it*256 + tid;          // 768 = 64 rows x 12 chunks
    int c = i / 12, cb = i % 12;
    *(bf16x8*)&KA[c][cb*8] = *(const bf16x8*)&Kc[(size_t)c*768 + h*96 + cb*8];
  }
  #pragma unroll
  for (int it=0; it<12; ++it){
    int i = it*256 + tid;          // 3072 = 128 rows x 24 f32x4
    int d = i / 24, q = i % 24;
    f32x4 v = *(const f32x4*)&Wq[(size_t)(kt*128+d)*768 + h*96 + q*4];
    WB[d][q*4+0]=f2bf(v[0]); WB[d][q*4+1]=f2bf(v[1]);
    WB[d][q*4+2]=f2bf(v[2]); WB[d][q*4+3]=f2bf(v[3]);
  }
  __syncthreads();
  f32x4 acc[4][2];
  #pragma unroll
  for (int i=0;i<4;++i){ acc[i][0]=(f32x4){0,0,0,0}; acc[i][1]=(f32x4){0,0,0,0}; }
  #pragma unroll
  for (int ks=0; ks<3; ++ks){
    bf16x8 a[4], b[2];
    #pragma unroll
    for (int mf=0; mf<4; ++mf) a[mf] = *(const bf16x8*)&KA[mf*16+l15][ks*32+g*8];
    #pragma unroll
    for (int nf=0; nf<2; ++nf) b[nf] = *(const bf16x8*)&WB[w*32+nf*16+l15][ks*32+g*8];
    #pragma unroll
    for (int mf=0; mf<4; ++mf)
      #pragma unroll
      for (int nf=0; nf<2; ++nf)
        acc[mf][nf] = MFMA(a[mf], b[nf], acc[mf][nf]);
  }
  size_t base = (size_t)((h>>1)*6 + kt)*16384;
  #pragma unroll
  for (int mf=0; mf<4; ++mf)
    #pragma unroll
    for (int nf=0; nf<2; ++nf)
      #pragma unroll
      for (int r=0; r<4; ++r){
        int c = mf*16 + g*4 + r;
        int d = w*32 + nf*16 + l15;
        int hcl = (h&1)*64 + c;
        WeffI[base + (size_t)hcl*128 + (((d>>3)^(hcl&7))<<3) + (d&7)] = f2bf(acc[mf][nf][r] * 0.10206207262f);
      }
}

// VWo image via MFMA: 48 blocks = h(8) x dt(6). Out[d][c] = Wo_h^T(128x96) @ V_h^T; img[d][hc].
__global__ __launch_bounds__(256) void prep_vwo(const float* __restrict__ Wo,
                        const short* __restrict__ VT, short* __restrict__ VWoI){
  __shared__ short WoT[128][104];  // A: [d][j]
  __shared__ short VA[64][104];    // B: [c][j]
  int h = blockIdx.x / 6, dt = blockIdx.x % 6, tid = threadIdx.x;
  const int lane = tid & 63, w = tid >> 6, l15 = lane & 15, g = lane >> 4;
  #pragma unroll
  for (int it=0; it<12; ++it){
    int i = it*256 + tid;          // 3072 = 96 rows x 32 f32x4
    int j = i / 32, qd = i % 32;
    f32x4 v = *(const f32x4*)&Wo[(size_t)(h*96+j)*768 + dt*128 + qd*4];
    WoT[qd*4+0][j]=f2bf(v[0]); WoT[qd*4+1][j]=f2bf(v[1]);
    WoT[qd*4+2][j]=f2bf(v[2]); WoT[qd*4+3][j]=f2bf(v[3]);
  }
  #pragma unroll
  for (int it=0; it<3; ++it){
    int i = it*256 + tid;          // 768 = 96 rows x 8 chunks
    int j = i / 8, cb = i % 8;
    bf16x8 v = *(const bf16x8*)&VT[(size_t)(h*96+j)*64 + cb*8];
    #pragma unroll
    for (int x=0; x<8; ++x) VA[cb*8+x][j] = v[x];
  }
  __syncthreads();
  f32x4 acc[2][4];
  #pragma unroll
  for (int i=0;i<2;++i)
    #pragma unroll
    for (int j=0;j<4;++j) acc[i][j]=(f32x4){0,0,0,0};
  #pragma unroll
  for (int ks=0; ks<3; ++ks){
    bf16x8 a[2], b[4];
    #pragma unroll
    for (int mf=0; mf<2; ++mf) a[mf] = *(const bf16x8*)&WoT[w*32+mf*16+l15][ks*32+g*8];
    #pragma unroll
    for (int nf=0; nf<4; ++nf) b[nf] = *(const bf16x8*)&VA[nf*16+l15][ks*32+g*8];
    #pragma unroll
    for (int mf=0; mf<2; ++mf)
      #pragma unroll
      for (int nf=0; nf<4; ++nf)
        acc[mf][nf] = MFMA(a[mf], b[nf], acc[mf][nf]);
  }
  size_t base = (size_t)(dt*4 + (h>>1))*16384;
  #pragma unroll
  for (int mf=0; mf<2; ++mf)
    #pragma unroll
    for (int nf=0; nf<4; ++nf)
      #pragma unroll
      for (int r=0; r<4; ++r){
        int d = w*32 + mf*16 + g*4 + r;
        int c = nf*16 + l15;
        int hcl = (h&1)*64 + c;
        VWoI[base + (size_t)d*128 + (((hcl>>3)^(d&7))<<3) + (hcl&7)] = f2bf(acc[mf][nf][r]);
      }
}

// hs f32 -> bf16 pre-swizzled hole1 + partial column sums. 512 blocks x 384 thr.
__global__ __launch_bounds__(384) void prep_hs(const float* __restrict__ hs,
                                               float* __restrict__ outp, float* __restrict__ tpp){
  __shared__ float csum[4][768];
  int tid = threadIdx.x;
  int c = tid % 96, rg = tid / 96;
  size_t r0 = (size_t)blockIdx.x * 128;
  u16* holes = (u16*)outp;
  float s[8];
  #pragma unroll
  for (int j=0;j<8;++j) s[j]=0.f;
  #pragma unroll 4
  for (int i=0; i<32; ++i){
    size_t row = r0 + rg*32 + i;
    const float* p = hs + row*768 + c*8;
    f32x4 x = __builtin_nontemporal_load((const f32x4*)p);
    f32x4 y = __builtin_nontemporal_load((const f32x4*)(p+4));
    *(bf16x8*)&holes[row*1536 + pch(c,(int)row)*8] = pack8(x,y);
    #pragma unroll
    for (int j=0;j<4;++j){ s[j]+=x[j]; s[4+j]+=y[j]; }
  }
  #pragma unroll
  for (int j=0;j<8;++j) csum[rg][c*8+j] = s[j];
  __syncthreads();
  for (int cc=tid; cc<768; cc+=384)
    tpp[(size_t)blockIdx.x*768 + cc] = csum[0][cc]+csum[1][cc]+csum[2][cc]+csum[3][cc];
}

__global__ void pool2(const float* __restrict__ tpp, float* __restrict__ tp){
  int b = blockIdx.x / 3, hc = blockIdx.x % 3;
  int h = hc*256 + threadIdx.x;
  float s = 0.f;
  #pragma unroll
  for (int k=0; k<32; ++k) s += tpp[((size_t)b*32 + k)*768 + h];
  tp[(size_t)b*768 + h] = s * (1.f/4096.f);
}
__global__ void pool3(const float* __restrict__ tp, const float* __restrict__ cp, float* __restrict__ rel){
  int b = blockIdx.x;
  float a=0.f, n1=0.f, n2=0.f;
  for (int h = threadIdx.x; h < 768; h += 256){
    float t = tp[(size_t)b*768 + h], c = cp[h];
    a += t*c; n1 += t*t; n2 += c*c;
  }
  #pragma unroll
  for (int m=1; m<64; m<<=1){ a+=__shfl_xor(a,m); n1+=__shfl_xor(n1,m); n2+=__shfl_xor(n2,m); }
  __shared__ float r3[3][4];
  int w = threadIdx.x >> 6;
  if ((threadIdx.x & 63) == 0){ r3[0][w]=a; r3[1][w]=n1; r3[2][w]=n2; }
  __syncthreads();
  if (threadIdx.x == 0){
    float A = r3[0][0]+r3[0][1]+r3[0][2]+r3[0][3];
    float N1= r3[1][0]+r3[1][1]+r3[1][2]+r3[1][3];
    float N2= r3[2][0]+r3[2][1]+r3[2][2]+r3[2][3];
    rel[b] = A / (fmaxf(sqrtf(N1),1e-8f) * fmaxf(sqrtf(N2),1e-8f));
  }
}

// ---------------- gs: S = hs @ Weff + sbias, per-head softmax fused -> attn bf16 in hole2 ----------------
__global__ __launch_bounds__(256) void gs(const short* __restrict__ WeffI,
                                          const float* __restrict__ sbias, float* outp){
  __shared__ short A0[8192], A1[8192], B0[8192], B1[8192];
  const int tid = threadIdx.x, lane = tid & 63, w = tid >> 6;
  const int l15 = lane & 15, g = lane >> 4;
  const int bid = blockIdx.x;
  const int nb = (bid >> 3) & 3, mt = (bid/32)*8 + (bid & 7);
  const int wm = w & 1, wn = w >> 1;
  const size_t t0 = (size_t)mt*128;
  u16* holes = (u16*)outp;
  const u16* Arow = holes + t0*1536;
  const short* Wimg = WeffI + (size_t)nb*6*16384;
  f32x4 acc[4][4];
  #pragma unroll
  for (int i=0;i<4;++i)
    #pragma unroll
    for (int j=0;j<4;++j) acc[i][j] = (f32x4){0.f,0.f,0.f,0.f};
  stA128(A0, Arow, 0, w, lane);
  stWB(B0, Wimg, 0, w, lane);
  __syncthreads();
  #pragma unroll
  for (int ks2=0; ks2<12; ++ks2){
    const short* Ac = (ks2&1)? A1 : A0;
    const short* Bc = (ks2&1)? B1 : B0;
    short* An = (ks2&1)? A0 : A1;
    short* Bn = (ks2&1)? B0 : B1;
    if (ks2<11){
      stA128(An, Arow, ks2+1, w, lane);
      stWB(Bn, Wimg + (size_t)(((ks2+1)>>1))*16384, (ks2+1)&1, w, lane);
    }
    #pragma unroll
    for (int ks=0; ks<2; ++ks){
      bf16x8 a[4], b[4];
      #pragma unroll
      for (int mf=0; mf<4; ++mf){ int r = wm*64+mf*16+l15; a[mf] = *(const bf16x8*)&Ac[r*64 + (((ks*4+g)^(r&7))<<3)]; }
      #pragma unroll
      for (int nf=0; nf<4; ++nf){ int r = wn*64+nf*16+l15; b[nf] = *(const bf16x8*)&Bc[r*64 + (((ks*4+g)^(r&7))<<3)]; }
      #pragma unroll
      for (int mf=0; mf<4; ++mf)
        #pragma unroll
        for (int nf=0; nf<4; ++nf)
          acc[mf][nf] = MFMA(a[mf], b[nf], acc[mf][nf]);
    }
    __syncthreads();
  }
  // epilogue: +sbias, per-head softmax (wave n-span == one head), write attn bf16
  #pragma unroll
  for (int mf=0; mf<4; ++mf)
    #pragma unroll
    for (int r=0; r<4; ++r){
      float v[4];
      #pragma unroll
      for (int nf=0; nf<4; ++nf)
        v[nf] = acc[mf][nf][r] + sbias[nb*128 + wn*64 + nf*16 + l15];
      float m = fmaxf(fmaxf(v[0],v[1]), fmaxf(v[2],v[3]));
      m = fmaxf(m,__shfl_xor(m,1)); m = fmaxf(m,__shfl_xor(m,2));
      m = fmaxf(m,__shfl_xor(m,4)); m = fmaxf(m,__shfl_xor(m,8));
      float e[4]; float s = 0.f;
      #pragma unroll
      for (int nf=0; nf<4; ++nf){ e[nf] = __expf(v[nf]-m); s += e[nf]; }
      s += __shfl_xor(s,1); s += __shfl_xor(s,2); s += __shfl_xor(s,4); s += __shfl_xor(s,8);
      float inv = 1.f/s;
      int grow = wm*64 + mf*16 + g*4 + r;
      #pragma unroll
      for (int nf=0; nf<4; ++nf){
        int col = nb*128 + wn*64 + nf*16 + l15;
        holes[(t0+grow)*1536 + 768 + pch(col>>3, grow)*8 + (col&7)] = (u16)f2bf(e[nf]*inv);
      }
    }
}

// ---------------- av: attn_avg only (read-only over attn) ----------------
__global__ __launch_bounds__(256) void av(float* outp){
  const int tid = threadIdx.x, lane = tid & 63, w = tid >> 6;
  u16* holes = (u16*)outp;
  #pragma unroll 1
  for (int i=0; i<8; ++i){
    int row = i*8192 + blockIdx.x*4 + w;
    const u16* p = &holes[(size_t)row*1536 + 768 + pch(lane,row)*8];
    bf16x8 v = *(const bf16x8*)p;
    float x[8];
    #pragma unroll
    for (int j=0;j<8;++j) x[j] = bf2f(v[j]);
    #pragma unroll
    for (int j=0;j<8;++j){
      x[j] += __shfl_xor(x[j],8); x[j] += __shfl_xor(x[j],16); x[j] += __shfl_xor(x[j],32);
      x[j] *= 0.125f;
    }
    if (lane < 8){
      f32x4 o0, o1;
      #pragma unroll
      for (int j=0;j<4;++j){ o0[j]=x[j]; o1[j]=x[4+j]; }
      float* ap = &outp[(size_t)50331648 + (size_t)row*64 + lane*8];
      __builtin_nontemporal_store(o0, (f32x4*)ap);
      __builtin_nontemporal_store(o1, (f32x4*)(ap+4));
    }
  }
}

// ---------------- gvwo: ctxo = attn @ VWo + bo -> hole2[0,768) (attn reg-staged first) ----------------
__global__ __launch_bounds__(256) void gvwo(const short* __restrict__ VWoI,
                                            const float* __restrict__ bo, float* outp){
  __shared__ short B0[8192], B1[8192];
  const int tid = threadIdx.x, lane = tid & 63, w = tid >> 6;
  const int l15 = lane & 15, g = lane >> 4;
  const size_t t0 = (size_t)blockIdx.x * 64;
  const int arow = w*16 + l15;
  const int drow = w*16 + g*4;
  u16* holes = (u16*)outp;
  bf16x8 af[16];
  #pragma unroll
  for (int kk=0; kk<16; ++kk){
    int kc = kk*4 + g;
    af[kk] = *(const bf16x8*)&holes[(t0+arow)*1536 + 768 + pch(kc, arow)*8];
  }
  stWB(B0, VWoI, 0, w, lane);
  __syncthreads();
  #pragma unroll 1
  for (int nb=0; nb<6; ++nb){
    f32x4 acc[8];
    #pragma unroll
    for (int i=0;i<8;++i) acc[i]=(f32x4){0.f,0.f,0.f,0.f};
    #pragma unroll
    for (int ks2=0; ks2<8; ++ks2){
      const short* Bc = (ks2&1)? B1 : B0;
      short* Bn = (ks2&1)? B0 : B1;
      if (ks2<7)       stWB(Bn, VWoI + (size_t)(nb*4 + ((ks2+1)>>1))*16384, (ks2+1)&1, w, lane);
      else if (nb<5)   stWB(Bn, VWoI + (size_t)((nb+1)*4)*16384, 0, w, lane);
      #pragma unroll
      for (int ks=0; ks<2; ++ks){
        bf16x8 a = af[ks2*2 + ks];
        #pragma unroll
        for (int nf=0; nf<8; ++nf){
          int br = nf*16 + l15;
          bf16x8 b = *(const bf16x8*)&Bc[br*64 + (((ks*4+g)^(br&7))<<3)];
          acc[nf] = MFMA(a, b, acc[nf]);
        }
      }
      __syncthreads();
    }
    #pragma unroll
    for (int nf=0; nf<8; ++nf)
      #pragma unroll
      for (int r=0; r<4; ++r){
        int row = drow + r;
        int col = nb*128 + nf*16 + l15;
        float v = acc[nf][r] + bo[col];
        holes[(t0+row)*1536 + 768 + pch(col>>3, row)*8 + (col&7)] = (u16)f2bf(v);
      }
  }
}

// ---------------- gate_mm: per-(mt,nb) block, K=1536 (both passes), partial relu-dot -> gpart ----------------
__global__ __launch_bounds__(256) void gate_mm(const short* __restrict__ WaI,
    const short* __restrict__ WbI, const float* __restrict__ bg1,
    const float* __restrict__ wg1c, const float* __restrict__ Wg2,
    const float* __restrict__ rel, float* __restrict__ gpart, float* outp){
  __shared__ short A0[8192], A1[8192], B0[8192], B1[8192];
  const int tid = threadIdx.x, lane = tid & 63, w = tid >> 6;
  const int l15 = lane & 15, g = lane >> 4;
  const int bid = blockIdx.x;
  const int nb = (bid >> 3) % 6, mt = (bid/48)*8 + (bid & 7);
  const int wm = w & 1, wn = w >> 1;
  const size_t t0 = (size_t)mt*128;
  const float relb = rel[t0 >> 12];
  u16* holes = (u16*)outp;
  const u16* h1p = holes + t0*1536;
  const u16* h2p = h1p + 768;
  f32x4 acc[4][4];
  #pragma unroll
  for (int i=0;i<4;++i)
    #pragma unroll
    for (int j=0;j<4;++j) acc[i][j]=(f32x4){0.f,0.f,0.f,0.f};
  stA128(A0, h1p, 0, w, lane);
  stWB(B0, WaI + (size_t)nb*6*16384, 0, w, lane);
  __syncthreads();
  #pragma unroll
  for (int pass=0; pass<2; ++pass){
    const short* Wimg = (pass? WbI : WaI) + (size_t)nb*6*16384;
    const u16* Ap = pass ? h2p : h1p;
    #pragma unroll
    for (int ks2=0; ks2<12; ++ks2){
      const short* Ac = (ks2&1)? A1 : A0;
      const short* Bc = (ks2&1)? B1 : B0;
      short* An = (ks2&1)? A0 : A1;
      short* Bn = (ks2&1)? B0 : B1;
      if (ks2<11){
        stA128(An, Ap, ks2+1, w, lane);
        stWB(Bn, Wimg + (size_t)(((ks2+1)>>1))*16384, (ks2+1)&1, w, lane);
      } else if (pass==0){
        stA128(An, h2p, 0, w, lane);
        stWB(Bn, WbI + (size_t)nb*6*16384, 0, w, lane);
      }
      #pragma unroll
      for (int ks=0; ks<2; ++ks){
        bf16x8 a[4], b[4];
        #pragma unroll
        for (int mf=0; mf<4; ++mf){ int r = wm*64+mf*16+l15; a[mf] = *(const bf16x8*)&Ac[r*64 + (((ks*4+g)^(r&7))<<3)]; }
        #pragma unroll
        for (int nf=0; nf<4; ++nf){ int r = wn*64+nf*16+l15; b[nf] = *(const bf16x8*)&Bc[r*64 + (((ks*4+g)^(r&7))<<3)]; }
        #pragma unroll
        for (int mf=0; mf<4; ++mf)
          #pragma unroll
          for (int nf=0; nf<4; ++nf)
            acc[mf][nf] = MFMA(a[mf], b[nf], acc[mf][nf]);
      }
      __syncthreads();
    }
  }
  float gp[4][4];
  #pragma unroll
  for (int mf=0; mf<4; ++mf)
    #pragma unroll
    for (int r=0; r<4; ++r) gp[mf][r]=0.f;
  #pragma unroll
  for (int mf=0; mf<4; ++mf)
    #pragma unroll
    for (int nf=0; nf<4; ++nf)
      #pragma unroll
      for (int r=0; r<4; ++r){
        int col = nb*128 + wn*64 + nf*16 + l15;
        gp[mf][r] += fmaxf(acc[mf][nf][r] + bg1[col] + relb*wg1c[col], 0.f) * Wg2[col];
      }
  #pragma unroll
  for (int mf=0; mf<4; ++mf)
    #pragma unroll
    for (int r=0; r<4; ++r){
      float v = gp[mf][r];
      v += __shfl_xor(v,1); v += __shfl_xor(v,2); v += __shfl_xor(v,4); v += __shfl_xor(v,8);
      gp[mf][r] = v;
    }
  __syncthreads();
  float* gred = (float*)B0;
  if (l15 == 0)
    #pragma unroll
    for (int mf=0; mf<4; ++mf)
      #pragma unroll
      for (int r=0; r<4; ++r)
        gred[wn*128 + wm*64 + mf*16 + g*4 + r] = gp[mf][r];
  __syncthreads();
  if (tid < 128)
    gpart[(size_t)nb*65536 + t0 + tid] = gred[tid] + gred[128+tid];
}

// ---------------- lnk: out = LN(hs + sigmoid(sum gpart + bg2)*ctxo) ----------------
__global__ __launch_bounds__(256) void lnk(const float* __restrict__ gpart,
    const float* __restrict__ bg2, const float* __restrict__ lng,
    const float* __restrict__ lnb, float* outp){
  const int tid = threadIdx.x, lane = tid & 63, w = tid >> 6;
  u16* holes = (u16*)outp;
  const float bg2v = bg2[0];
  #pragma unroll 1
  for (int i=0; i<8; ++i){
    int row = blockIdx.x*32 + w*8 + i;
    float gsum = bg2v;
    #pragma unroll
    for (int nb2=0; nb2<6; ++nb2) gsum += gpart[(size_t)nb2*65536 + row];
    float gg = 1.f/(1.f + __expf(-gsum));
    int c1 = lane, c2 = 64 + (lane & 31);
    size_t rb = (size_t)row*1536;
    bf16x8 hv1 = *(const bf16x8*)&holes[rb + pch(c1,row)*8];
    bf16x8 ov1 = *(const bf16x8*)&holes[rb + 768 + pch(c1,row)*8];
    bf16x8 hv2 = *(const bf16x8*)&holes[rb + pch(c2,row)*8];
    bf16x8 ov2 = *(const bf16x8*)&holes[rb + 768 + pch(c2,row)*8];
    float x1[8], x2[8];
    float sum=0.f, sq=0.f;
    #pragma unroll
    for (int j=0;j<8;++j){ float x = bf2f(hv1[j]) + gg*bf2f(ov1[j]); x1[j]=x; sum+=x; sq+=x*x; }
    if (lane < 32){
      #pragma unroll
      for (int j=0;j<8;++j){ float x = bf2f(hv2[j]) + gg*bf2f(ov2[j]); x2[j]=x; sum+=x; sq+=x*x; }
    }
    #pragma unroll
    for (int m=1; m<64; m<<=1){ sum += __shfl_xor(sum,m); sq += __shfl_xor(sq,m); }
    float mu = sum * (1.f/768.f);
    float var = sq * (1.f/768.f) - mu*mu;
    float rs = rsqrtf(var + 1e-5f);
    {
      f32x4 ga = *(const f32x4*)&lng[c1*8], gb = *(const f32x4*)&lng[c1*8+4];
      f32x4 ba = *(const f32x4*)&lnb[c1*8], bb = *(const f32x4*)&lnb[c1*8+4];
      f32x4 o0, o1;
      #pragma unroll
      for (int j=0;j<4;++j){ o0[j] = (x1[j]-mu)*rs*ga[j]+ba[j]; o1[j] = (x1[4+j]-mu)*rs*gb[j]+bb[j]; }
      *(f32x4*)&outp[(size_t)row*768 + c1*8] = o0;
      *(f32x4*)&outp[(size_t)row*768 + c1*8 + 4] = o1;
    }
    if (lane < 32){
      f32x4 ga = *(const f32x4*)&lng[c2*8], gb = *(const f32x4*)&lng[c2*8+4];
      f32x4 ba = *(const f32x4*)&lnb[c2*8], bb = *(const f32x4*)&lnb[c2*8+4];
      f32x4 o0, o1;
      #pragma unroll
      for (int j=0;j<4;++j){ o0[j] = (x2[j]-mu)*rs*ga[j]+ba[j]; o1[j] = (x2[4+j]-mu)*rs*gb[j]+bb[j]; }
      *(f32x4*)&outp[(size_t)row*768 + c2*8] = o0;
      *(f32x4*)&outp[(size_t)row*768 + c2*8 + 4] = o1;
    }
  }
}

extern "C" void kernel_launch(void* const* d_in, const int* in_sizes, int n_in,
                              void* d_out, int out_size, void* d_ws, size_t ws_size,
                              hipStream_t stream) {
  (void)in_sizes; (void)n_in; (void)out_size; (void)ws_size;
  const float* hs  = (const float*)d_in[0];
  const float* ce  = (const float*)d_in[1];
  const float* Wq  = (const float*)d_in[2];
  const float* bq  = (const float*)d_in[3];
  const float* Wk  = (const float*)d_in[4];
  const float* bk  = (const float*)d_in[5];
  const float* Wv  = (const float*)d_in[6];
  const float* bv  = (const float*)d_in[7];
  const float* Wo  = (const float*)d_in[8];
  const float* bo  = (const float*)d_in[9];
  const float* Wg1 = (const float*)d_in[10];
  const float* bg1 = (const float*)d_in[11];
  const float* Wg2 = (const float*)d_in[12];
  const float* bg2 = (const float*)d_in[13];
  const float* lng = (const float*)d_in[14];
  const float* lnb = (const float*)d_in[15];
  char* ws = (char*)d_ws;
  short* WeffI = (short*)(ws + 0);         // 24 * 32KB
  short* VWoI  = (short*)(ws + 1179648);   // 24 * 32KB
  short* WaI   = (short*)(ws + 2359296);
  short* WbI   = (short*)(ws + 3538944);
  short* Kc    = (short*)(ws + 4718592);
  short* VT    = (short*)(ws + 4816896);
  float* wg1c  = (float*)(ws + 4915200);
  float* cp    = (float*)(ws + 4918272);
  float* tp    = (float*)(ws + 4921344);
  float* rel   = (float*)(ws + 4970496);
  float* tpp   = (float*)(ws + 4970752);
  float* gpart = (float*)(ws + 4970752);   // aliases tpp (dead by gate_mm)
  float* sbias = (float*)(ws + 6543616);
  float* outp  = (float*)d_out;

  prep_kv  <<<96,  256, 0, stream>>>(ce, Wk, bk, Wv, bv, Kc, VT);
  prep_w   <<<72,  256, 0, stream>>>(Wg1, WaI, WbI);
  prep_misc<<<17,  256, 0, stream>>>(Wg1, ce, bq, Kc, wg1c, cp, sbias);
  prep_eff <<<48,  256, 0, stream>>>(Wq, Kc, WeffI);
  prep_vwo <<<48,  256, 0, stream>>>(Wo, VT, VWoI);
  prep_hs  <<<512, 384, 0, stream>>>(hs, outp, tpp);
  pool2    <<<48,  256, 0, stream>>>(tpp, tp);
  pool3    <<<16,  256, 0, stream>>>(tp, cp, rel);
  gs       <<<2048,256, 0, stream>>>(WeffI, sbias, outp);
  av       <<<2048,256, 0, stream>>>(outp);
  gvwo     <<<1024,256, 0, stream>>>(VWoI, bo, outp);
  gate_mm  <<<3072,256, 0, stream>>>(WaI, WbI, bg1, wg1c, Wg2, rel, gpart, outp);
  lnk      <<<2048,256, 0, stream>>>(gpart, bg2, lng, lnb, outp);
}

// Round 11
// 503.942 us; speedup vs baseline: 1.6272x; 1.0687x over previous
//
#include <hip/hip_runtime.h>

typedef __attribute__((ext_vector_type(8))) short bf16x8;
typedef __attribute__((ext_vector_type(4))) float f32x4;
typedef unsigned short u16;

#define MFMA(a,b,c) __builtin_amdgcn_mfma_f32_16x16x32_bf16((a),(b),(c),0,0,0)

__device__ __forceinline__ short f2bf(float f){
  union { float f; unsigned u; } v; v.f = f;
  unsigned r = v.u + 0x7FFFu + ((v.u >> 16) & 1u);
  return (short)(r >> 16);
}
__device__ __forceinline__ float bf2f(short s){
  union { unsigned u; float f; } v; v.u = ((unsigned)(unsigned short)s) << 16; return v.f;
}
__device__ __forceinline__ bf16x8 pack8(f32x4 x, f32x4 y){
  bf16x8 r;
  r[0]=f2bf(x[0]); r[1]=f2bf(x[1]); r[2]=f2bf(x[2]); r[3]=f2bf(x[3]);
  r[4]=f2bf(y[0]); r[5]=f2bf(y[1]); r[6]=f2bf(y[2]); r[7]=f2bf(y[3]);
  return r;
}
// hole swizzle: physical 16B-chunk index for logical chunk c of row
__device__ __forceinline__ int pch(int c, int row){ return (c & ~7) | ((c & 7) ^ (row & 7)); }

__device__ __forceinline__ void gload16(void* lp, const void* gp){
  __builtin_amdgcn_global_load_lds((const __attribute__((address_space(1))) unsigned*)gp,
                                   (__attribute__((address_space(3))) unsigned*)lp, 16, 0, 0);
}
// ---- 256-thread staging helpers (16KB) ----
__device__ __forceinline__ void stWB(short* buf, const short* img, int half, int w, int lane){
  const char* gp = (const char*)img;
  #pragma unroll
  for (int it=0; it<4; ++it){
    int id = it*256 + w*64 + lane; int r = id>>3, c = id&7;
    gload16((char*)buf + it*4096 + w*1024, gp + r*256 + half*128 + c*16);
  }
}
__device__ __forceinline__ void stA128(short* buf, const u16* rowb, int kstep, int w, int lane){
  #pragma unroll
  for (int it=0; it<4; ++it){
    int id = it*256 + w*64 + lane; int r = id>>3, c = id&7;
    gload16((char*)buf + it*4096 + w*1024, rowb + (size_t)r*1536 + (kstep*8 + c)*8);
  }
}
// ---- 512-thread staging helpers (32KB: 256 rows x 8 chunks) ----
__device__ __forceinline__ void stA256(short* buf, const u16* rowb, int kstep, int w, int lane){
  int tid = w*64 + lane;
  #pragma unroll
  for (int it=0; it<4; ++it){
    int id = it*512 + tid; int r = id>>3, c = id&7;
    gload16((char*)buf + it*8192 + w*1024, rowb + (size_t)r*1536 + (kstep*8 + c)*8);
  }
}
// img points at block (jt0*6+kt); rows 128.. come from block (jt0+1)*6+kt (stride 98304 shorts)
__device__ __forceinline__ void stB256(short* buf, const short* img, int half, int w, int lane){
  int tid = w*64 + lane;
  #pragma unroll
  for (int it=0; it<4; ++it){
    int id = it*512 + tid; int r = id>>3, c = id&7;
    gload16((char*)buf + it*8192 + w*1024,
            img + (size_t)(r>>7)*98304 + (size_t)(r&127)*128 + half*64 + c*8);
  }
}

// ---------------- prep kernels ----------------
__global__ void prep_w(const float* __restrict__ Wg1, short* __restrict__ WaI, short* __restrict__ WbI){
  __shared__ short lt[128][136];
  int blk = blockIdx.x;            // 72 = 2 mats * 6 kt * 6 jt
  int mat = blk / 36, t = blk % 36, kt = t / 6, jt = t % 6;
  const float* src = (mat==0)? Wg1 : (Wg1 + (size_t)768*768);
  short* dst = (mat==0)? WaI : WbI;
  int tid = threadIdx.x;
  #pragma unroll
  for (int it=0; it<16; ++it){
    int kl = it*8 + (tid>>5);
    int jl = (tid&31)*4;
    f32x4 v = *(const f32x4*)&src[(size_t)(kt*128+kl)*768 + jt*128 + jl];
    lt[jl+0][kl]=f2bf(v[0]); lt[jl+1][kl]=f2bf(v[1]);
    lt[jl+2][kl]=f2bf(v[2]); lt[jl+3][kl]=f2bf(v[3]);
  }
  __syncthreads();
  size_t base = (size_t)(jt*6 + kt)*16384;
  #pragma unroll
  for (int cc=0; cc<8; ++cc){
    int ci = cc*256 + tid;
    int jl = ci >> 4, sc = ci & 15;
    int kkb = ((sc ^ (jl & 7)) << 3);
    bf16x8 v = *(const bf16x8*)&lt[jl][kkb];
    *(bf16x8*)&dst[base + (size_t)jl*128 + sc*8] = v;
  }
}

__global__ __launch_bounds__(256) void prep_kv(const float* __restrict__ ce,
                        const float* __restrict__ Wk, const float* __restrict__ bk,
                        const float* __restrict__ Wv, const float* __restrict__ bv,
                        short* __restrict__ Kc, short* __restrict__ VT){
  __shared__ float sh[8][768];
  int jt = blockIdx.x / 8, cg = blockIdx.x % 8;
  int tid = threadIdx.x;
  int j = jt*64 + (tid & 63);
  int cl = tid >> 6;
  for (int i = tid; i < 8*768; i += 256){
    int c2 = i / 768; int h = i - c2*768;
    sh[c2][h] = ce[(size_t)(cg*8+c2)*768 + h];
  }
  __syncthreads();
  float aK0=0.f, aV0=0.f, aK1=0.f, aV1=0.f;
  #pragma unroll 4
  for (int h=0; h<768; ++h){
    float wk = Wk[(size_t)h*768 + j];
    float wv = Wv[(size_t)h*768 + j];
    float x0 = sh[cl*2][h], x1 = sh[cl*2+1][h];
    aK0 += x0*wk; aV0 += x0*wv;
    aK1 += x1*wk; aV1 += x1*wv;
  }
  float bkj = bk[j], bvj = bv[j];
  int c0 = cg*8 + cl*2;
  Kc[(size_t)c0*768 + j]     = f2bf(aK0 + bkj);
  Kc[(size_t)(c0+1)*768 + j] = f2bf(aK1 + bkj);
  VT[(size_t)j*64 + c0]      = f2bf(aV0 + bvj);
  VT[(size_t)j*64 + c0+1]    = f2bf(aV1 + bvj);
}

// 17 blocks: 0-11 wg1c; 12-14 cp; 15-16 sbias
__global__ void prep_misc(const float* __restrict__ Wg1, const float* __restrict__ ce,
                          const float* __restrict__ bq, const short* __restrict__ Kc,
                          float* __restrict__ wg1c, float* __restrict__ cp,
                          float* __restrict__ sbias){
  __shared__ float red[4][64];
  int b = blockIdx.x, tid = threadIdx.x;
  if (b < 12){
    int j = b*64 + (tid & 63);
    int kq = tid >> 6;
    float s = 0.f;
    for (int r=0; r<192; ++r)
      s += Wg1[(size_t)(1536 + kq*192 + r)*768 + j];
    red[kq][tid&63] = s;
    __syncthreads();
    if (tid < 64) wg1c[b*64+tid] = red[0][tid]+red[1][tid]+red[2][tid]+red[3][tid];
  } else if (b < 15){
    int h = (b-12)*256 + tid;
    float s = 0.f;
    #pragma unroll
    for (int c2=0; c2<64; ++c2) s += ce[(size_t)c2*768 + h];
    cp[h] = s * (1.f/64.f);
  } else {
    int hc = (b-15)*256 + tid;
    int h = hc >> 6, c = hc & 63;
    float s = 0.f;
    #pragma unroll
    for (int j=0; j<96; ++j)
      s += bq[h*96+j] * bf2f(Kc[(size_t)c*768 + h*96 + j]);
    sbias[hc] = s * 0.10206207262f;
  }
}

// Weff image via MFMA: 48 blocks = h(8) x kt(6)
__global__ __launch_bounds__(256) void prep_eff(const float* __restrict__ Wq,
                        const short* __restrict__ Kc, short* __restrict__ WeffI){
  __shared__ short KA[64][104];
  __shared__ short WB[128][104];
  int h = blockIdx.x / 6, kt = blockIdx.x % 6, tid = threadIdx.x;
  const int lane = tid & 63, w = tid >> 6, l15 = lane & 15, g = lane >> 4;
  #pragma unroll
  for (int it=0; it<3; ++it){
    int i = it*256 + tid;
    int c = i / 12, cb = i % 12;
    *(bf16x8*)&KA[c][cb*8] = *(const bf16x8*)&Kc[(size_t)c*768 + h*96 + cb*8];
  }
  #pragma unroll
  for (int it=0; it<12; ++it){
    int i = it*256 + tid;
    int d = i / 24, q = i % 24;
    f32x4 v = *(const f32x4*)&Wq[(size_t)(kt*128+d)*768 + h*96 + q*4];
    WB[d][q*4+0]=f2bf(v[0]); WB[d][q*4+1]=f2bf(v[1]);
    WB[d][q*4+2]=f2bf(v[2]); WB[d][q*4+3]=f2bf(v[3]);
  }
  __syncthreads();
  f32x4 acc[4][2];
  #pragma unroll
  for (int i=0;i<4;++i){ acc[i][0]=(f32x4){0,0,0,0}; acc[i][1]=(f32x4){0,0,0,0}; }
  #pragma unroll
  for (int ks=0; ks<3; ++ks){
    bf16x8 a[4], b[2];
    #pragma unroll
    for (int mf=0; mf<4; ++mf) a[mf] = *(const bf16x8*)&KA[mf*16+l15][ks*32+g*8];
    #pragma unroll
    for (int nf=0; nf<2; ++nf) b[nf] = *(const bf16x8*)&WB[w*32+nf*16+l15][ks*32+g*8];
    #pragma unroll
    for (int mf=0; mf<4; ++mf)
      #pragma unroll
      for (int nf=0; nf<2; ++nf)
        acc[mf][nf] = MFMA(a[mf], b[nf], acc[mf][nf]);
  }
  size_t base = (size_t)((h>>1)*6 + kt)*16384;
  #pragma unroll
  for (int mf=0; mf<4; ++mf)
    #pragma unroll
    for (int nf=0; nf<2; ++nf)
      #pragma unroll
      for (int r=0; r<4; ++r){
        int c = mf*16 + g*4 + r;
        int d = w*32 + nf*16 + l15;
        int hcl = (h&1)*64 + c;
        WeffI[base + (size_t)hcl*128 + (((d>>3)^(hcl&7))<<3) + (d&7)] = f2bf(acc[mf][nf][r] * 0.10206207262f);
      }
}

// VWo image via MFMA: 48 blocks = h(8) x dt(6)
__global__ __launch_bounds__(256) void prep_vwo(const float* __restrict__ Wo,
                        const short* __restrict__ VT, short* __restrict__ VWoI){
  __shared__ short WoT[128][104];
  __shared__ short VA[64][104];
  int h = blockIdx.x / 6, dt = blockIdx.x % 6, tid = threadIdx.x;
  const int lane = tid & 63, w = tid >> 6, l15 = lane & 15, g = lane >> 4;
  #pragma unroll
  for (int it=0; it<12; ++it){
    int i = it*256 + tid;
    int j = i / 32, qd = i % 32;
    f32x4 v = *(const f32x4*)&Wo[(size_t)(h*96+j)*768 + dt*128 + qd*4];
    WoT[qd*4+0][j]=f2bf(v[0]); WoT[qd*4+1][j]=f2bf(v[1]);
    WoT[qd*4+2][j]=f2bf(v[2]); WoT[qd*4+3][j]=f2bf(v[3]);
  }
  #pragma unroll
  for (int it=0; it<3; ++it){
    int i = it*256 + tid;
    int j = i / 8, cb = i % 8;
    bf16x8 v = *(const bf16x8*)&VT[(size_t)(h*96+j)*64 + cb*8];
    #pragma unroll
    for (int x=0; x<8; ++x) VA[cb*8+x][j] = v[x];
  }
  __syncthreads();
  f32x4 acc[2][4];
  #pragma unroll
  for (int i=0;i<2;++i)
    #pragma unroll
    for (int j=0;j<4;++j) acc[i][j]=(f32x4){0,0,0,0};
  #pragma unroll
  for (int ks=0; ks<3; ++ks){
    bf16x8 a[2], b[4];
    #pragma unroll
    for (int mf=0; mf<2; ++mf) a[mf] = *(const bf16x8*)&WoT[w*32+mf*16+l15][ks*32+g*8];
    #pragma unroll
    for (int nf=0; nf<4; ++nf) b[nf] = *(const bf16x8*)&VA[nf*16+l15][ks*32+g*8];
    #pragma unroll
    for (int mf=0; mf<2; ++mf)
      #pragma unroll
      for (int nf=0; nf<4; ++nf)
        acc[mf][nf] = MFMA(a[mf], b[nf], acc[mf][nf]);
  }
  size_t base = (size_t)(dt*4 + (h>>1))*16384;
  #pragma unroll
  for (int mf=0; mf<2; ++mf)
    #pragma unroll
    for (int nf=0; nf<4; ++nf)
      #pragma unroll
      for (int r=0; r<4; ++r){
        int d = w*32 + mf*16 + g*4 + r;
        int c = nf*16 + l15;
        int hcl = (h&1)*64 + c;
        VWoI[base + (size_t)d*128 + (((hcl>>3)^(d&7))<<3) + (hcl&7)] = f2bf(acc[mf][nf][r]);
      }
}

// hs f32 -> bf16 pre-swizzled hole1 + partial column sums. 512 blocks x 384 thr.
__global__ __launch_bounds__(384) void prep_hs(const float* __restrict__ hs,
                                               float* __restrict__ outp, float* __restrict__ tpp){
  __shared__ float csum[4][768];
  int tid = threadIdx.x;
  int c = tid % 96, rg = tid / 96;
  size_t r0 = (size_t)blockIdx.x * 128;
  u16* holes = (u16*)outp;
  float s[8];
  #pragma unroll
  for (int j=0;j<8;++j) s[j]=0.f;
  #pragma unroll 4
  for (int i=0; i<32; ++i){
    size_t row = r0 + rg*32 + i;
    const float* p = hs + row*768 + c*8;
    f32x4 x = __builtin_nontemporal_load((const f32x4*)p);
    f32x4 y = __builtin_nontemporal_load((const f32x4*)(p+4));
    *(bf16x8*)&holes[row*1536 + pch(c,(int)row)*8] = pack8(x,y);
    #pragma unroll
    for (int j=0;j<4;++j){ s[j]+=x[j]; s[4+j]+=y[j]; }
  }
  #pragma unroll
  for (int j=0;j<8;++j) csum[rg][c*8+j] = s[j];
  __syncthreads();
  for (int cc=tid; cc<768; cc+=384)
    tpp[(size_t)blockIdx.x*768 + cc] = csum[0][cc]+csum[1][cc]+csum[2][cc]+csum[3][cc];
}

// merged pool2+pool3: 16 blocks x 256 thr
__global__ void pool23(const float* __restrict__ tpp, const float* __restrict__ cp,
                       float* __restrict__ rel){
  int b = blockIdx.x;
  float a=0.f, n1=0.f, n2=0.f;
  for (int h = threadIdx.x; h < 768; h += 256){
    float s = 0.f;
    #pragma unroll
    for (int k=0; k<32; ++k) s += tpp[((size_t)b*32 + k)*768 + h];
    s *= (1.f/4096.f);
    float c = cp[h];
    a += s*c; n1 += s*s; n2 += c*c;
  }
  #pragma unroll
  for (int m=1; m<64; m<<=1){ a+=__shfl_xor(a,m); n1+=__shfl_xor(n1,m); n2+=__shfl_xor(n2,m); }
  __shared__ float r3[3][4];
  int w = threadIdx.x >> 6;
  if ((threadIdx.x & 63) == 0){ r3[0][w]=a; r3[1][w]=n1; r3[2][w]=n2; }
  __syncthreads();
  if (threadIdx.x == 0){
    float A = r3[0][0]+r3[0][1]+r3[0][2]+r3[0][3];
    float N1= r3[1][0]+r3[1][1]+r3[1][2]+r3[1][3];
    float N2= r3[2][0]+r3[2][1]+r3[2][2]+r3[2][3];
    rel[b] = A / (fmaxf(sqrtf(N1),1e-8f) * fmaxf(sqrtf(N2),1e-8f));
  }
}

// ---------------- gs: S = hs @ Weff + sbias, per-head softmax fused -> attn bf16 in hole2 ----------------
__global__ __launch_bounds__(256) void gs(const short* __restrict__ WeffI,
                                          const float* __restrict__ sbias, float* outp){
  __shared__ short A0[8192], A1[8192], B0[8192], B1[8192];
  const int tid = threadIdx.x, lane = tid & 63, w = tid >> 6;
  const int l15 = lane & 15, g = lane >> 4;
  const int bid = blockIdx.x;
  const int nb = (bid >> 3) & 3, mt = (bid/32)*8 + (bid & 7);
  const int wm = w & 1, wn = w >> 1;
  const size_t t0 = (size_t)mt*128;
  u16* holes = (u16*)outp;
  const u16* Arow = holes + t0*1536;
  const short* Wimg = WeffI + (size_t)nb*6*16384;
  f32x4 acc[4][4];
  #pragma unroll
  for (int i=0;i<4;++i)
    #pragma unroll
    for (int j=0;j<4;++j) acc[i][j] = (f32x4){0.f,0.f,0.f,0.f};
  stA128(A0, Arow, 0, w, lane);
  stWB(B0, Wimg, 0, w, lane);
  __syncthreads();
  #pragma unroll
  for (int ks2=0; ks2<12; ++ks2){
    const short* Ac = (ks2&1)? A1 : A0;
    const short* Bc = (ks2&1)? B1 : B0;
    short* An = (ks2&1)? A0 : A1;
    short* Bn = (ks2&1)? B0 : B1;
    if (ks2<11){
      stA128(An, Arow, ks2+1, w, lane);
      stWB(Bn, Wimg + (size_t)(((ks2+1)>>1))*16384, (ks2+1)&1, w, lane);
    }
    #pragma unroll
    for (int ks=0; ks<2; ++ks){
      bf16x8 a[4], b[4];
      #pragma unroll
      for (int mf=0; mf<4; ++mf){ int r = wm*64+mf*16+l15; a[mf] = *(const bf16x8*)&Ac[r*64 + (((ks*4+g)^(r&7))<<3)]; }
      #pragma unroll
      for (int nf=0; nf<4; ++nf){ int r = wn*64+nf*16+l15; b[nf] = *(const bf16x8*)&Bc[r*64 + (((ks*4+g)^(r&7))<<3)]; }
      #pragma unroll
      for (int mf=0; mf<4; ++mf)
        #pragma unroll
        for (int nf=0; nf<4; ++nf)
          acc[mf][nf] = MFMA(a[mf], b[nf], acc[mf][nf]);
    }
    __syncthreads();
  }
  #pragma unroll
  for (int mf=0; mf<4; ++mf)
    #pragma unroll
    for (int r=0; r<4; ++r){
      float v[4];
      #pragma unroll
      for (int nf=0; nf<4; ++nf)
        v[nf] = acc[mf][nf][r] + sbias[nb*128 + wn*64 + nf*16 + l15];
      float m = fmaxf(fmaxf(v[0],v[1]), fmaxf(v[2],v[3]));
      m = fmaxf(m,__shfl_xor(m,1)); m = fmaxf(m,__shfl_xor(m,2));
      m = fmaxf(m,__shfl_xor(m,4)); m = fmaxf(m,__shfl_xor(m,8));
      float e[4]; float s = 0.f;
      #pragma unroll
      for (int nf=0; nf<4; ++nf){ e[nf] = __expf(v[nf]-m); s += e[nf]; }
      s += __shfl_xor(s,1); s += __shfl_xor(s,2); s += __shfl_xor(s,4); s += __shfl_xor(s,8);
      float inv = 1.f/s;
      int grow = wm*64 + mf*16 + g*4 + r;
      #pragma unroll
      for (int nf=0; nf<4; ++nf){
        int col = nb*128 + wn*64 + nf*16 + l15;
        holes[(t0+grow)*1536 + 768 + pch(col>>3, grow)*8 + (col&7)] = (u16)f2bf(e[nf]*inv);
      }
    }
}

// ---------------- gvwo: ctxo = attn @ VWo + bo -> hole2[0,768); attn_avg fused from regs ----------------
__global__ __launch_bounds__(256) void gvwo(const short* __restrict__ VWoI,
                                            const float* __restrict__ bo, float* outp){
  __shared__ short B0[8192], B1[8192];
  const int tid = threadIdx.x, lane = tid & 63, w = tid >> 6;
  const int l15 = lane & 15, g = lane >> 4;
  const size_t t0 = (size_t)blockIdx.x * 64;
  const int arow = w*16 + l15;
  const int drow = w*16 + g*4;
  u16* holes = (u16*)outp;
  bf16x8 af[16];
  #pragma unroll
  for (int kk=0; kk<16; ++kk){
    int kc = kk*4 + g;
    af[kk] = *(const bf16x8*)&holes[(t0+arow)*1536 + 768 + pch(kc, arow)*8];
  }
  stWB(B0, VWoI, 0, w, lane);
  // fused attn_avg: thread holds head-chunks {g (kk even), 4+g (kk odd)} for all 8 heads
  {
    float s0[8], s1[8];
    #pragma unroll
    for (int j=0;j<8;++j){ s0[j]=0.f; s1[j]=0.f; }
    #pragma unroll
    for (int kk=0; kk<16; kk+=2)
      #pragma unroll
      for (int j=0;j<8;++j) s0[j] += bf2f(af[kk][j]);
    #pragma unroll
    for (int kk=1; kk<16; kk+=2)
      #pragma unroll
      for (int j=0;j<8;++j) s1[j] += bf2f(af[kk][j]);
    float* ap = &outp[(size_t)50331648 + (size_t)(t0+arow)*64];
    f32x4 o;
    #pragma unroll
    for (int j=0;j<4;++j) o[j] = s0[j]*0.125f;
    __builtin_nontemporal_store(o, (f32x4*)(ap + g*8));
    #pragma unroll
    for (int j=0;j<4;++j) o[j] = s0[4+j]*0.125f;
    __builtin_nontemporal_store(o, (f32x4*)(ap + g*8 + 4));
    #pragma unroll
    for (int j=0;j<4;++j) o[j] = s1[j]*0.125f;
    __builtin_nontemporal_store(o, (f32x4*)(ap + (4+g)*8));
    #pragma unroll
    for (int j=0;j<4;++j) o[j] = s1[4+j]*0.125f;
    __builtin_nontemporal_store(o, (f32x4*)(ap + (4+g)*8 + 4));
  }
  __syncthreads();
  #pragma unroll 1
  for (int nb=0; nb<6; ++nb){
    f32x4 acc[8];
    #pragma unroll
    for (int i=0;i<8;++i) acc[i]=(f32x4){0.f,0.f,0.f,0.f};
    #pragma unroll
    for (int ks2=0; ks2<8; ++ks2){
      const short* Bc = (ks2&1)? B1 : B0;
      short* Bn = (ks2&1)? B0 : B1;
      if (ks2<7)       stWB(Bn, VWoI + (size_t)(nb*4 + ((ks2+1)>>1))*16384, (ks2+1)&1, w, lane);
      else if (nb<5)   stWB(Bn, VWoI + (size_t)((nb+1)*4)*16384, 0, w, lane);
      #pragma unroll
      for (int ks=0; ks<2; ++ks){
        bf16x8 a = af[ks2*2 + ks];
        #pragma unroll
        for (int nf=0; nf<8; ++nf){
          int br = nf*16 + l15;
          bf16x8 b = *(const bf16x8*)&Bc[br*64 + (((ks*4+g)^(br&7))<<3)];
          acc[nf] = MFMA(a, b, acc[nf]);
        }
      }
      __syncthreads();
    }
    #pragma unroll
    for (int nf=0; nf<8; ++nf)
      #pragma unroll
      for (int r=0; r<4; ++r){
        int row = drow + r;
        int col = nb*128 + nf*16 + l15;
        float v = acc[nf][r] + bo[col];
        holes[(t0+row)*1536 + 768 + pch(col>>3, row)*8 + (col&7)] = (u16)f2bf(v);
      }
  }
}

// ---------------- gate_mm: 256x256 tile, 512 thr, 8 waves (2M x 4N), K=1536 -> gpart (3 nb) ----------------
__global__ void __launch_bounds__(512)
__attribute__((amdgpu_waves_per_eu(2, 2))) gate_mm(const short* __restrict__ WaI,
    const short* __restrict__ WbI, const float* __restrict__ bg1,
    const float* __restrict__ wg1c, const float* __restrict__ Wg2,
    const float* __restrict__ rel, float* __restrict__ gpart, float* outp){
  extern __shared__ char lds[];
  short* A0 = (short*)lds;                 // 32KB: 256 rows x 64 shorts
  short* A1 = (short*)(lds + 32768);
  short* B0 = (short*)(lds + 65536);
  short* B1 = (short*)(lds + 98304);
  const int tid = threadIdx.x, lane = tid & 63, w = tid >> 6;
  const int l15 = lane & 15, g = lane >> 4;
  const int bid = blockIdx.x;              // 768 = 256 mt x 3 nb
  const int nb = (bid >> 3) % 3, mt = (bid/24)*8 + (bid & 7);
  const int wm = w & 1, wn = w >> 1;       // wave tile: 128M x 64N
  const size_t t0 = (size_t)mt*256;
  const float relb = rel[t0 >> 12];
  u16* holes = (u16*)outp;
  const u16* h1p = holes + t0*1536;
  const u16* h2p = h1p + 768;
  f32x4 acc[8][4];
  #pragma unroll
  for (int i=0;i<8;++i)
    #pragma unroll
    for (int j=0;j<4;++j) acc[i][j]=(f32x4){0.f,0.f,0.f,0.f};
  stA256(A0, h1p, 0, w, lane);
  stB256(B0, WaI + (size_t)(nb*2)*98304, 0, w, lane);
  __syncthreads();
  #pragma unroll 1
  for (int pass=0; pass<2; ++pass){
    const short* Wimg = pass ? (WbI + (size_t)(nb*2)*98304) : (WaI + (size_t)(nb*2)*98304);
    const u16* Ap = pass ? h2p : h1p;
    #pragma unroll
    for (int ks2=0; ks2<12; ++ks2){
      const short* Ac = (ks2&1)? A1 : A0;
      const short* Bc = (ks2&1)? B1 : B0;
      short* An = (ks2&1)? A0 : A1;
      short* Bn = (ks2&1)? B0 : B1;
      if (ks2<11){
        stA256(An, Ap, ks2+1, w, lane);
        stB256(Bn, Wimg + (size_t)((ks2+1)>>1)*16384, (ks2+1)&1, w, lane);
      } else if (pass==0){
        stA256(An, h2p, 0, w, lane);
        stB256(Bn, WbI + (size_t)(nb*2)*98304, 0, w, lane);
      }
      #pragma unroll
      for (int ks=0; ks<2; ++ks){
        bf16x8 a[8], b[4];
        #pragma unroll
        for (int mf=0; mf<8; ++mf){ int r = wm*128+mf*16+l15; a[mf] = *(const bf16x8*)&Ac[r*64 + (((ks*4+g)^(r&7))<<3)]; }
        #pragma unroll
        for (int nf=0; nf<4; ++nf){ int r = wn*64+nf*16+l15; b[nf] = *(const bf16x8*)&Bc[r*64 + (((ks*4+g)^(r&7))<<3)]; }
        #pragma unroll
        for (int mf=0; mf<8; ++mf)
          #pragma unroll
          for (int nf=0; nf<4; ++nf)
            acc[mf][nf] = MFMA(a[mf], b[nf], acc[mf][nf]);
      }
      __syncthreads();
    }
  }
  // epilogue: bias+rel, relu, dot Wg2 -> per-row partials
  float gp[8][4];
  #pragma unroll
  for (int mf=0; mf<8; ++mf)
    #pragma unroll
    for (int r=0; r<4; ++r) gp[mf][r]=0.f;
  #pragma unroll
  for (int mf=0; mf<8; ++mf)
    #pragma unroll
    for (int nf=0; nf<4; ++nf)
      #pragma unroll
      for (int r=0; r<4; ++r){
        int col = nb*256 + wn*64 + nf*16 + l15;
        gp[mf][r] += fmaxf(acc[mf][nf][r] + bg1[col] + relb*wg1c[col], 0.f) * Wg2[col];
      }
  #pragma unroll
  for (int mf=0; mf<8; ++mf)
    #pragma unroll
    for (int r=0; r<4; ++r){
      float v = gp[mf][r];
      v += __shfl_xor(v,1); v += __shfl_xor(v,2); v += __shfl_xor(v,4); v += __shfl_xor(v,8);
      gp[mf][r] = v;
    }
  float* gred = (float*)lds;   // 4 x 256 floats; A0 dead after final barrier
  if (l15 == 0)
    #pragma unroll
    for (int mf=0; mf<8; ++mf)
      #pragma unroll
      for (int r=0; r<4; ++r)
        gred[wn*256 + wm*128 + mf*16 + g*4 + r] = gp[mf][r];
  __syncthreads();
  if (tid < 256)
    gpart[(size_t)nb*65536 + t0 + tid] = gred[tid] + gred[256+tid] + gred[512+tid] + gred[768+tid];
}

// ---------------- lnk: out = LN(hs + sigmoid(sum gpart + bg2)*ctxo) ----------------
__global__ __launch_bounds__(256) void lnk(const float* __restrict__ gpart,
    const float* __restrict__ bg2, const float* __restrict__ lng,
    const float* __restrict__ lnb, float* outp){
  const int tid = threadIdx.x, lane = tid & 63, w = tid >> 6;
  u16* holes = (u16*)outp;
  const float bg2v = bg2[0];
  #pragma unroll 1
  for (int i=0; i<8; ++i){
    int row = blockIdx.x*32 + w*8 + i;
    float gsum = bg2v;
    #pragma unroll
    for (int nb2=0; nb2<3; ++nb2) gsum += gpart[(size_t)nb2*65536 + row];
    float gg = 1.f/(1.f + __expf(-gsum));
    int c1 = lane, c2 = 64 + (lane & 31);
    size_t rb = (size_t)row*1536;
    bf16x8 hv1 = *(const bf16x8*)&holes[rb + pch(c1,row)*8];
    bf16x8 ov1 = *(const bf16x8*)&holes[rb + 768 + pch(c1,row)*8];
    bf16x8 hv2 = *(const bf16x8*)&holes[rb + pch(c2,row)*8];
    bf16x8 ov2 = *(const bf16x8*)&holes[rb + 768 + pch(c2,row)*8];
    float x1[8], x2[8];
    float sum=0.f, sq=0.f;
    #pragma unroll
    for (int j=0;j<8;++j){ float x = bf2f(hv1[j]) + gg*bf2f(ov1[j]); x1[j]=x; sum+=x; sq+=x*x; }
    if (lane < 32){
      #pragma unroll
      for (int j=0;j<8;++j){ float x = bf2f(hv2[j]) + gg*bf2f(ov2[j]); x2[j]=x; sum+=x; sq+=x*x; }
    }
    #pragma unroll
    for (int m=1; m<64; m<<=1){ sum += __shfl_xor(sum,m); sq += __shfl_xor(sq,m); }
    float mu = sum * (1.f/768.f);
    float var = sq * (1.f/768.f) - mu*mu;
    float rs = rsqrtf(var + 1e-5f);
    {
      f32x4 ga = *(const f32x4*)&lng[c1*8], gb = *(const f32x4*)&lng[c1*8+4];
      f32x4 ba = *(const f32x4*)&lnb[c1*8], bb = *(const f32x4*)&lnb[c1*8+4];
      f32x4 o0, o1;
      #pragma unroll
      for (int j=0;j<4;++j){ o0[j] = (x1[j]-mu)*rs*ga[j]+ba[j]; o1[j] = (x1[4+j]-mu)*rs*gb[j]+bb[j]; }
      *(f32x4*)&outp[(size_t)row*768 + c1*8] = o0;
      *(f32x4*)&outp[(size_t)row*768 + c1*8 + 4] = o1;
    }
    if (lane < 32){
      f32x4 ga = *(const f32x4*)&lng[c2*8], gb = *(const f32x4*)&lng[c2*8+4];
      f32x4 ba = *(const f32x4*)&lnb[c2*8], bb = *(const f32x4*)&lnb[c2*8+4];
      f32x4 o0, o1;
      #pragma unroll
      for (int j=0;j<4;++j){ o0[j] = (x2[j]-mu)*rs*ga[j]+ba[j]; o1[j] = (x2[4+j]-mu)*rs*gb[j]+bb[j]; }
      *(f32x4*)&outp[(size_t)row*768 + c2*8] = o0;
      *(f32x4*)&outp[(size_t)row*768 + c2*8 + 4] = o1;
    }
  }
}

extern "C" void kernel_launch(void* const* d_in, const int* in_sizes, int n_in,
                              void* d_out, int out_size, void* d_ws, size_t ws_size,
                              hipStream_t stream) {
  (void)in_sizes; (void)n_in; (void)out_size; (void)ws_size;
  const float* hs  = (const float*)d_in[0];
  const float* ce  = (const float*)d_in[1];
  const float* Wq  = (const float*)d_in[2];
  const float* bq  = (const float*)d_in[3];
  const float* Wk  = (const float*)d_in[4];
  const float* bk  = (const float*)d_in[5];
  const float* Wv  = (const float*)d_in[6];
  const float* bv  = (const float*)d_in[7];
  const float* Wo  = (const float*)d_in[8];
  const float* bo  = (const float*)d_in[9];
  const float* Wg1 = (const float*)d_in[10];
  const float* bg1 = (const float*)d_in[11];
  const float* Wg2 = (const float*)d_in[12];
  const float* bg2 = (const float*)d_in[13];
  const float* lng = (const float*)d_in[14];
  const float* lnb = (const float*)d_in[15];
  char* ws = (char*)d_ws;
  short* WeffI = (short*)(ws + 0);
  short* VWoI  = (short*)(ws + 1179648);
  short* WaI   = (short*)(ws + 2359296);
  short* WbI   = (short*)(ws + 3538944);
  short* Kc    = (short*)(ws + 4718592);
  short* VT    = (short*)(ws + 4816896);
  float* wg1c  = (float*)(ws + 4915200);
  float* cp    = (float*)(ws + 4918272);
  float* rel   = (float*)(ws + 4970496);
  float* tpp   = (float*)(ws + 4970752);
  float* gpart = (float*)(ws + 4970752);   // aliases tpp (dead by gate_mm); 3*65536*4
  float* sbias = (float*)(ws + 6543616);
  float* outp  = (float*)d_out;

  prep_kv  <<<96,  256, 0, stream>>>(ce, Wk, bk, Wv, bv, Kc, VT);
  prep_w   <<<72,  256, 0, stream>>>(Wg1, WaI, WbI);
  prep_misc<<<17,  256, 0, stream>>>(Wg1, ce, bq, Kc, wg1c, cp, sbias);
  prep_eff <<<48,  256, 0, stream>>>(Wq, Kc, WeffI);
  prep_vwo <<<48,  256, 0, stream>>>(Wo, VT, VWoI);
  prep_hs  <<<512, 384, 0, stream>>>(hs, outp, tpp);
  pool23   <<<16,  256, 0, stream>>>(tpp, cp, rel);
  gs       <<<2048,256, 0, stream>>>(WeffI, sbias, outp);
  gvwo     <<<1024,256, 0, stream>>>(VWoI, bo, outp);
  hipFuncSetAttribute(reinterpret_cast<const void*>(gate_mm),
                      hipFuncAttributeMaxDynamicSharedMemorySize, 131072);
  gate_mm  <<<768, 512, 131072, stream>>>(WaI, WbI, bg1, wg1c, Wg2, rel, gpart, outp);
  lnk      <<<2048,256, 0, stream>>>(gpart, bg2, lng, lnb, outp);
}

// Round 13
// 500.628 us; speedup vs baseline: 1.6379x; 1.0066x over previous
//
#include <hip/hip_runtime.h>

typedef __attribute__((ext_vector_type(8))) short bf16x8;
typedef __attribute__((ext_vector_type(4))) float f32x4;
typedef unsigned short u16;

#define MFMA(a,b,c) __builtin_amdgcn_mfma_f32_16x16x32_bf16((a),(b),(c),0,0,0)

__device__ __forceinline__ short f2bf(float f){
  union { float f; unsigned u; } v; v.f = f;
  unsigned r = v.u + 0x7FFFu + ((v.u >> 16) & 1u);
  return (short)(r >> 16);
}
__device__ __forceinline__ float bf2f(short s){
  union { unsigned u; float f; } v; v.u = ((unsigned)(unsigned short)s) << 16; return v.f;
}
__device__ __forceinline__ bf16x8 pack8(f32x4 x, f32x4 y){
  bf16x8 r;
  r[0]=f2bf(x[0]); r[1]=f2bf(x[1]); r[2]=f2bf(x[2]); r[3]=f2bf(x[3]);
  r[4]=f2bf(y[0]); r[5]=f2bf(y[1]); r[6]=f2bf(y[2]); r[7]=f2bf(y[3]);
  return r;
}
// hole swizzle: physical 16B-chunk index for logical chunk c of row
__device__ __forceinline__ int pch(int c, int row){ return (c & ~7) | ((c & 7) ^ (row & 7)); }

__device__ __forceinline__ void gload16(void* lp, const void* gp){
  __builtin_amdgcn_global_load_lds((const __attribute__((address_space(1))) unsigned*)gp,
                                   (__attribute__((address_space(3))) unsigned*)lp, 16, 0, 0);
}
// ---- 256-thread staging helpers (16KB) ----
__device__ __forceinline__ void stWB(short* buf, const short* img, int half, int w, int lane){
  const char* gp = (const char*)img;
  #pragma unroll
  for (int it=0; it<4; ++it){
    int id = it*256 + w*64 + lane; int r = id>>3, c = id&7;
    gload16((char*)buf + it*4096 + w*1024, gp + r*256 + half*128 + c*16);
  }
}
__device__ __forceinline__ void stA128(short* buf, const u16* rowb, int kstep, int w, int lane){
  #pragma unroll
  for (int it=0; it<4; ++it){
    int id = it*256 + w*64 + lane; int r = id>>3, c = id&7;
    gload16((char*)buf + it*4096 + w*1024, rowb + (size_t)r*1536 + (kstep*8 + c)*8);
  }
}
// ---- 512-thread staging helpers (32KB: 256 rows x 8 chunks) ----
__device__ __forceinline__ void stA256(short* buf, const u16* rowb, int kstep, int w, int lane){
  int tid = w*64 + lane;
  #pragma unroll
  for (int it=0; it<4; ++it){
    int id = it*512 + tid; int r = id>>3, c = id&7;
    gload16((char*)buf + it*8192 + w*1024, rowb + (size_t)r*1536 + (kstep*8 + c)*8);
  }
}
// img points at block (jt0*6+kt); rows 128.. come from block (jt0+1)*6+kt (stride 98304 shorts)
__device__ __forceinline__ void stB256(short* buf, const short* img, int half, int w, int lane){
  int tid = w*64 + lane;
  #pragma unroll
  for (int it=0; it<4; ++it){
    int id = it*512 + tid; int r = id>>3, c = id&7;
    gload16((char*)buf + it*8192 + w*1024,
            img + (size_t)(r>>7)*98304 + (size_t)(r&127)*128 + half*64 + c*8);
  }
}

// ---------------- prep kernels ----------------
__global__ void prep_w(const float* __restrict__ Wg1, short* __restrict__ WaI, short* __restrict__ WbI){
  __shared__ short lt[128][136];
  int blk = blockIdx.x;            // 72 = 2 mats * 6 kt * 6 jt
  int mat = blk / 36, t = blk % 36, kt = t / 6, jt = t % 6;
  const float* src = (mat==0)? Wg1 : (Wg1 + (size_t)768*768);
  short* dst = (mat==0)? WaI : WbI;
  int tid = threadIdx.x;
  #pragma unroll
  for (int it=0; it<16; ++it){
    int kl = it*8 + (tid>>5);
    int jl = (tid&31)*4;
    f32x4 v = *(const f32x4*)&src[(size_t)(kt*128+kl)*768 + jt*128 + jl];
    lt[jl+0][kl]=f2bf(v[0]); lt[jl+1][kl]=f2bf(v[1]);
    lt[jl+2][kl]=f2bf(v[2]); lt[jl+3][kl]=f2bf(v[3]);
  }
  __syncthreads();
  size_t base = (size_t)(jt*6 + kt)*16384;
  #pragma unroll
  for (int cc=0; cc<8; ++cc){
    int ci = cc*256 + tid;
    int jl = ci >> 4, sc = ci & 15;
    int kkb = ((sc ^ (jl & 7)) << 3);
    bf16x8 v = *(const bf16x8*)&lt[jl][kkb];
    *(bf16x8*)&dst[base + (size_t)jl*128 + sc*8] = v;
  }
}

__global__ __launch_bounds__(256) void prep_kv(const float* __restrict__ ce,
                        const float* __restrict__ Wk, const float* __restrict__ bk,
                        const float* __restrict__ Wv, const float* __restrict__ bv,
                        short* __restrict__ Kc, short* __restrict__ VT){
  __shared__ float sh[8][768];
  int jt = blockIdx.x / 8, cg = blockIdx.x % 8;
  int tid = threadIdx.x;
  int j = jt*64 + (tid & 63);
  int cl = tid >> 6;
  for (int i = tid; i < 8*768; i += 256){
    int c2 = i / 768; int h = i - c2*768;
    sh[c2][h] = ce[(size_t)(cg*8+c2)*768 + h];
  }
  __syncthreads();
  float aK0=0.f, aV0=0.f, aK1=0.f, aV1=0.f;
  #pragma unroll 4
  for (int h=0; h<768; ++h){
    float wk = Wk[(size_t)h*768 + j];
    float wv = Wv[(size_t)h*768 + j];
    float x0 = sh[cl*2][h], x1 = sh[cl*2+1][h];
    aK0 += x0*wk; aV0 += x0*wv;
    aK1 += x1*wk; aV1 += x1*wv;
  }
  float bkj = bk[j], bvj = bv[j];
  int c0 = cg*8 + cl*2;
  Kc[(size_t)c0*768 + j]     = f2bf(aK0 + bkj);
  Kc[(size_t)(c0+1)*768 + j] = f2bf(aK1 + bkj);
  VT[(size_t)j*64 + c0]      = f2bf(aV0 + bvj);
  VT[(size_t)j*64 + c0+1]    = f2bf(aV1 + bvj);
}

// 17 blocks: 0-11 wg1c; 12-14 cp; 15-16 sbias
__global__ void prep_misc(const float* __restrict__ Wg1, const float* __restrict__ ce,
                          const float* __restrict__ bq, const short* __restrict__ Kc,
                          float* __restrict__ wg1c, float* __restrict__ cp,
                          float* __restrict__ sbias){
  __shared__ float red[4][64];
  int b = blockIdx.x, tid = threadIdx.x;
  if (b < 12){
    int j = b*64 + (tid & 63);
    int kq = tid >> 6;
    float s = 0.f;
    for (int r=0; r<192; ++r)
      s += Wg1[(size_t)(1536 + kq*192 + r)*768 + j];
    red[kq][tid&63] = s;
    __syncthreads();
    if (tid < 64) wg1c[b*64+tid] = red[0][tid]+red[1][tid]+red[2][tid]+red[3][tid];
  } else if (b < 15){
    int h = (b-12)*256 + tid;
    float s = 0.f;
    #pragma unroll
    for (int c2=0; c2<64; ++c2) s += ce[(size_t)c2*768 + h];
    cp[h] = s * (1.f/64.f);
  } else {
    int hc = (b-15)*256 + tid;
    int h = hc >> 6, c = hc & 63;
    float s = 0.f;
    #pragma unroll
    for (int j=0; j<96; ++j)
      s += bq[h*96+j] * bf2f(Kc[(size_t)c*768 + h*96 + j]);
    sbias[hc] = s * 0.10206207262f;
  }
}

// Weff image via MFMA: 48 blocks = h(8) x kt(6)
__global__ __launch_bounds__(256) void prep_eff(const float* __restrict__ Wq,
                        const short* __restrict__ Kc, short* __restrict__ WeffI){
  __shared__ short KA[64][104];
  __shared__ short WB[128][104];
  int h = blockIdx.x / 6, kt = blockIdx.x % 6, tid = threadIdx.x;
  const int lane = tid & 63, w = tid >> 6, l15 = lane & 15, g = lane >> 4;
  #pragma unroll
  for (int it=0; it<3; ++it){
    int i = it*256 + tid;
    int c = i / 12, cb = i % 12;
    *(bf16x8*)&KA[c][cb*8] = *(const bf16x8*)&Kc[(size_t)c*768 + h*96 + cb*8];
  }
  #pragma unroll
  for (int it=0; it<12; ++it){
    int i = it*256 + tid;
    int d = i / 24, q = i % 24;
    f32x4 v = *(const f32x4*)&Wq[(size_t)(kt*128+d)*768 + h*96 + q*4];
    WB[d][q*4+0]=f2bf(v[0]); WB[d][q*4+1]=f2bf(v[1]);
    WB[d][q*4+2]=f2bf(v[2]); WB[d][q*4+3]=f2bf(v[3]);
  }
  __syncthreads();
  f32x4 acc[4][2];
  #pragma unroll
  for (int i=0;i<4;++i){ acc[i][0]=(f32x4){0,0,0,0}; acc[i][1]=(f32x4){0,0,0,0}; }
  #pragma unroll
  for (int ks=0; ks<3; ++ks){
    bf16x8 a[4], b[2];
    #pragma unroll
    for (int mf=0; mf<4; ++mf) a[mf] = *(const bf16x8*)&KA[mf*16+l15][ks*32+g*8];
    #pragma unroll
    for (int nf=0; nf<2; ++nf) b[nf] = *(const bf16x8*)&WB[w*32+nf*16+l15][ks*32+g*8];
    #pragma unroll
    for (int mf=0; mf<4; ++mf)
      #pragma unroll
      for (int nf=0; nf<2; ++nf)
        acc[mf][nf] = MFMA(a[mf], b[nf], acc[mf][nf]);
  }
  size_t base = (size_t)((h>>1)*6 + kt)*16384;
  #pragma unroll
  for (int mf=0; mf<4; ++mf)
    #pragma unroll
    for (int nf=0; nf<2; ++nf)
      #pragma unroll
      for (int r=0; r<4; ++r){
        int c = mf*16 + g*4 + r;
        int d = w*32 + nf*16 + l15;
        int hcl = (h&1)*64 + c;
        WeffI[base + (size_t)hcl*128 + (((d>>3)^(hcl&7))<<3) + (d&7)] = f2bf(acc[mf][nf][r] * 0.10206207262f);
      }
}

// VWo image via MFMA: 48 blocks = h(8) x dt(6)
__global__ __launch_bounds__(256) void prep_vwo(const float* __restrict__ Wo,
                        const short* __restrict__ VT, short* __restrict__ VWoI){
  __shared__ short WoT[128][104];
  __shared__ short VA[64][104];
  int h = blockIdx.x / 6, dt = blockIdx.x % 6, tid = threadIdx.x;
  const int lane = tid & 63, w = tid >> 6, l15 = lane & 15, g = lane >> 4;
  #pragma unroll
  for (int it=0; it<12; ++it){
    int i = it*256 + tid;
    int j = i / 32, qd = i % 32;
    f32x4 v = *(const f32x4*)&Wo[(size_t)(h*96+j)*768 + dt*128 + qd*4];
    WoT[qd*4+0][j]=f2bf(v[0]); WoT[qd*4+1][j]=f2bf(v[1]);
    WoT[qd*4+2][j]=f2bf(v[2]); WoT[qd*4+3][j]=f2bf(v[3]);
  }
  #pragma unroll
  for (int it=0; it<3; ++it){
    int i = it*256 + tid;
    int j = i / 8, cb = i % 8;
    bf16x8 v = *(const bf16x8*)&VT[(size_t)(h*96+j)*64 + cb*8];
    #pragma unroll
    for (int x=0; x<8; ++x) VA[cb*8+x][j] = v[x];
  }
  __syncthreads();
  f32x4 acc[2][4];
  #pragma unroll
  for (int i=0;i<2;++i)
    #pragma unroll
    for (int j=0;j<4;++j) acc[i][j]=(f32x4){0,0,0,0};
  #pragma unroll
  for (int ks=0; ks<3; ++ks){
    bf16x8 a[2], b[4];
    #pragma unroll
    for (int mf=0; mf<2; ++mf) a[mf] = *(const bf16x8*)&WoT[w*32+mf*16+l15][ks*32+g*8];
    #pragma unroll
    for (int nf=0; nf<4; ++nf) b[nf] = *(const bf16x8*)&VA[nf*16+l15][ks*32+g*8];
    #pragma unroll
    for (int mf=0; mf<2; ++mf)
      #pragma unroll
      for (int nf=0; nf<4; ++nf)
        acc[mf][nf] = MFMA(a[mf], b[nf], acc[mf][nf]);
  }
  size_t base = (size_t)(dt*4 + (h>>1))*16384;
  #pragma unroll
  for (int mf=0; mf<2; ++mf)
    #pragma unroll
    for (int nf=0; nf<4; ++nf)
      #pragma unroll
      for (int r=0; r<4; ++r){
        int d = w*32 + mf*16 + g*4 + r;
        int c = nf*16 + l15;
        int hcl = (h&1)*64 + c;
        VWoI[base + (size_t)d*128 + (((hcl>>3)^(d&7))<<3) + (hcl&7)] = f2bf(acc[mf][nf][r]);
      }
}

// hs f32 -> bf16 pre-swizzled hole1 + partial column sums. 512 blocks x 384 thr.
__global__ __launch_bounds__(384) void prep_hs(const float* __restrict__ hs,
                                               float* __restrict__ outp, float* __restrict__ tpp){
  __shared__ float csum[4][768];
  int tid = threadIdx.x;
  int c = tid % 96, rg = tid / 96;
  size_t r0 = (size_t)blockIdx.x * 128;
  u16* holes = (u16*)outp;
  float s[8];
  #pragma unroll
  for (int j=0;j<8;++j) s[j]=0.f;
  #pragma unroll 4
  for (int i=0; i<32; ++i){
    size_t row = r0 + rg*32 + i;
    const float* p = hs + row*768 + c*8;
    f32x4 x = __builtin_nontemporal_load((const f32x4*)p);
    f32x4 y = __builtin_nontemporal_load((const f32x4*)(p+4));
    *(bf16x8*)&holes[row*1536 + pch(c,(int)row)*8] = pack8(x,y);
    #pragma unroll
    for (int j=0;j<4;++j){ s[j]+=x[j]; s[4+j]+=y[j]; }
  }
  #pragma unroll
  for (int j=0;j<8;++j) csum[rg][c*8+j] = s[j];
  __syncthreads();
  for (int cc=tid; cc<768; cc+=384)
    tpp[(size_t)blockIdx.x*768 + cc] = csum[0][cc]+csum[1][cc]+csum[2][cc]+csum[3][cc];
}

// merged pool2+pool3: 16 blocks x 256 thr
__global__ void pool23(const float* __restrict__ tpp, const float* __restrict__ cp,
                       float* __restrict__ rel){
  int b = blockIdx.x;
  float a=0.f, n1=0.f, n2=0.f;
  for (int h = threadIdx.x; h < 768; h += 256){
    float s = 0.f;
    #pragma unroll
    for (int k=0; k<32; ++k) s += tpp[((size_t)b*32 + k)*768 + h];
    s *= (1.f/4096.f);
    float c = cp[h];
    a += s*c; n1 += s*s; n2 += c*c;
  }
  #pragma unroll
  for (int m=1; m<64; m<<=1){ a+=__shfl_xor(a,m); n1+=__shfl_xor(n1,m); n2+=__shfl_xor(n2,m); }
  __shared__ float r3[3][4];
  int w = threadIdx.x >> 6;
  if ((threadIdx.x & 63) == 0){ r3[0][w]=a; r3[1][w]=n1; r3[2][w]=n2; }
  __syncthreads();
  if (threadIdx.x == 0){
    float A = r3[0][0]+r3[0][1]+r3[0][2]+r3[0][3];
    float N1= r3[1][0]+r3[1][1]+r3[1][2]+r3[1][3];
    float N2= r3[2][0]+r3[2][1]+r3[2][2]+r3[2][3];
    rel[b] = A / (fmaxf(sqrtf(N1),1e-8f) * fmaxf(sqrtf(N2),1e-8f));
  }
}

// ---------------- gs: S = hs @ Weff + sbias, per-head softmax fused -> attn bf16 in hole2 ----------------
__global__ __launch_bounds__(256) void gs(const short* __restrict__ WeffI,
                                          const float* __restrict__ sbias, float* outp){
  __shared__ short A0[8192], A1[8192], B0[8192], B1[8192];
  const int tid = threadIdx.x, lane = tid & 63, w = tid >> 6;
  const int l15 = lane & 15, g = lane >> 4;
  const int bid = blockIdx.x;
  const int nb = (bid >> 3) & 3, mt = (bid/32)*8 + (bid & 7);
  const int wm = w & 1, wn = w >> 1;
  const size_t t0 = (size_t)mt*128;
  u16* holes = (u16*)outp;
  const u16* Arow = holes + t0*1536;
  const short* Wimg = WeffI + (size_t)nb*6*16384;
  f32x4 acc[4][4];
  #pragma unroll
  for (int i=0;i<4;++i)
    #pragma unroll
    for (int j=0;j<4;++j) acc[i][j] = (f32x4){0.f,0.f,0.f,0.f};
  stA128(A0, Arow, 0, w, lane);
  stWB(B0, Wimg, 0, w, lane);
  __syncthreads();
  #pragma unroll
  for (int ks2=0; ks2<12; ++ks2){
    const short* Ac = (ks2&1)? A1 : A0;
    const short* Bc = (ks2&1)? B1 : B0;
    short* An = (ks2&1)? A0 : A1;
    short* Bn = (ks2&1)? B0 : B1;
    if (ks2<11){
      stA128(An, Arow, ks2+1, w, lane);
      stWB(Bn, Wimg + (size_t)(((ks2+1)>>1))*16384, (ks2+1)&1, w, lane);
    }
    #pragma unroll
    for (int ks=0; ks<2; ++ks){
      bf16x8 a[4], b[4];
      #pragma unroll
      for (int mf=0; mf<4; ++mf){ int r = wm*64+mf*16+l15; a[mf] = *(const bf16x8*)&Ac[r*64 + (((ks*4+g)^(r&7))<<3)]; }
      #pragma unroll
      for (int nf=0; nf<4; ++nf){ int r = wn*64+nf*16+l15; b[nf] = *(const bf16x8*)&Bc[r*64 + (((ks*4+g)^(r&7))<<3)]; }
      #pragma unroll
      for (int mf=0; mf<4; ++mf)
        #pragma unroll
        for (int nf=0; nf<4; ++nf)
          acc[mf][nf] = MFMA(a[mf], b[nf], acc[mf][nf]);
    }
    __syncthreads();
  }
  #pragma unroll
  for (int mf=0; mf<4; ++mf)
    #pragma unroll
    for (int r=0; r<4; ++r){
      float v[4];
      #pragma unroll
      for (int nf=0; nf<4; ++nf)
        v[nf] = acc[mf][nf][r] + sbias[nb*128 + wn*64 + nf*16 + l15];
      float m = fmaxf(fmaxf(v[0],v[1]), fmaxf(v[2],v[3]));
      m = fmaxf(m,__shfl_xor(m,1)); m = fmaxf(m,__shfl_xor(m,2));
      m = fmaxf(m,__shfl_xor(m,4)); m = fmaxf(m,__shfl_xor(m,8));
      float e[4]; float s = 0.f;
      #pragma unroll
      for (int nf=0; nf<4; ++nf){ e[nf] = __expf(v[nf]-m); s += e[nf]; }
      s += __shfl_xor(s,1); s += __shfl_xor(s,2); s += __shfl_xor(s,4); s += __shfl_xor(s,8);
      float inv = 1.f/s;
      int grow = wm*64 + mf*16 + g*4 + r;
      #pragma unroll
      for (int nf=0; nf<4; ++nf){
        int col = nb*128 + wn*64 + nf*16 + l15;
        holes[(t0+grow)*1536 + 768 + pch(col>>3, grow)*8 + (col&7)] = (u16)f2bf(e[nf]*inv);
      }
    }
}

// ---------------- gvwo: ctxo = attn @ VWo + bo -> hole2[0,768); attn_avg fused from regs ----------------
__global__ __launch_bounds__(256) void gvwo(const short* __restrict__ VWoI,
                                            const float* __restrict__ bo, float* outp){
  __shared__ short B0[8192], B1[8192];
  const int tid = threadIdx.x, lane = tid & 63, w = tid >> 6;
  const int l15 = lane & 15, g = lane >> 4;
  const size_t t0 = (size_t)blockIdx.x * 64;
  const int arow = w*16 + l15;
  const int drow = w*16 + g*4;
  u16* holes = (u16*)outp;
  bf16x8 af[16];
  #pragma unroll
  for (int kk=0; kk<16; ++kk){
    int kc = kk*4 + g;
    af[kk] = *(const bf16x8*)&holes[(t0+arow)*1536 + 768 + pch(kc, arow)*8];
  }
  stWB(B0, VWoI, 0, w, lane);
  {
    float s0[8], s1[8];
    #pragma unroll
    for (int j=0;j<8;++j){ s0[j]=0.f; s1[j]=0.f; }
    #pragma unroll
    for (int kk=0; kk<16; kk+=2)
      #pragma unroll
      for (int j=0;j<8;++j) s0[j] += bf2f(af[kk][j]);
    #pragma unroll
    for (int kk=1; kk<16; kk+=2)
      #pragma unroll
      for (int j=0;j<8;++j) s1[j] += bf2f(af[kk][j]);
    float* ap = &outp[(size_t)50331648 + (size_t)(t0+arow)*64];
    f32x4 o;
    #pragma unroll
    for (int j=0;j<4;++j) o[j] = s0[j]*0.125f;
    __builtin_nontemporal_store(o, (f32x4*)(ap + g*8));
    #pragma unroll
    for (int j=0;j<4;++j) o[j] = s0[4+j]*0.125f;
    __builtin_nontemporal_store(o, (f32x4*)(ap + g*8 + 4));
    #pragma unroll
    for (int j=0;j<4;++j) o[j] = s1[j]*0.125f;
    __builtin_nontemporal_store(o, (f32x4*)(ap + (4+g)*8));
    #pragma unroll
    for (int j=0;j<4;++j) o[j] = s1[4+j]*0.125f;
    __builtin_nontemporal_store(o, (f32x4*)(ap + (4+g)*8 + 4));
  }
  __syncthreads();
  #pragma unroll 1
  for (int nb=0; nb<6; ++nb){
    f32x4 acc[8];
    #pragma unroll
    for (int i=0;i<8;++i) acc[i]=(f32x4){0.f,0.f,0.f,0.f};
    #pragma unroll
    for (int ks2=0; ks2<8; ++ks2){
      const short* Bc = (ks2&1)? B1 : B0;
      short* Bn = (ks2&1)? B0 : B1;
      if (ks2<7)       stWB(Bn, VWoI + (size_t)(nb*4 + ((ks2+1)>>1))*16384, (ks2+1)&1, w, lane);
      else if (nb<5)   stWB(Bn, VWoI + (size_t)((nb+1)*4)*16384, 0, w, lane);
      #pragma unroll
      for (int ks=0; ks<2; ++ks){
        bf16x8 a = af[ks2*2 + ks];
        #pragma unroll
        for (int nf=0; nf<8; ++nf){
          int br = nf*16 + l15;
          bf16x8 b = *(const bf16x8*)&Bc[br*64 + (((ks*4+g)^(br&7))<<3)];
          acc[nf] = MFMA(a, b, acc[nf]);
        }
      }
      __syncthreads();
    }
    #pragma unroll
    for (int nf=0; nf<8; ++nf)
      #pragma unroll
      for (int r=0; r<4; ++r){
        int row = drow + r;
        int col = nb*128 + nf*16 + l15;
        float v = acc[nf][r] + bo[col];
        holes[(t0+row)*1536 + 768 + pch(col>>3, row)*8 + (col&7)] = (u16)f2bf(v);
      }
  }
}

// ---------------- gate_mm: 256x256 tile, 512 thr, 8 waves (2M x 4N), K=1536 -> gpart (3 nb) ----------------
__global__ void __launch_bounds__(512)
__attribute__((amdgpu_waves_per_eu(2, 2))) gate_mm(const short* __restrict__ WaI,
    const short* __restrict__ WbI, const float* __restrict__ bg1,
    const float* __restrict__ wg1c, const float* __restrict__ Wg2,
    const float* __restrict__ rel, float* __restrict__ gpart, float* outp){
  extern __shared__ char lds[];
  short* A0 = (short*)lds;                 // 32KB: 256 rows x 64 shorts
  short* A1 = (short*)(lds + 32768);
  short* B0 = (short*)(lds + 65536);
  short* B1 = (short*)(lds + 98304);
  const int tid = threadIdx.x, lane = tid & 63, w = tid >> 6;
  const int l15 = lane & 15, g = lane >> 4;
  const int bid = blockIdx.x;              // 768 = 256 mt x 3 nb
  const int nb = (bid >> 3) % 3, mt = (bid/24)*8 + (bid & 7);
  const int wm = w & 1, wn = w >> 1;       // wave tile: 128M x 64N
  const size_t t0 = (size_t)mt*256;
  const float relb = rel[t0 >> 12];
  u16* holes = (u16*)outp;
  const u16* h1p = holes + t0*1536;
  const u16* h2p = h1p + 768;
  f32x4 acc[8][4];
  #pragma unroll
  for (int i=0;i<8;++i)
    #pragma unroll
    for (int j=0;j<4;++j) acc[i][j]=(f32x4){0.f,0.f,0.f,0.f};
  stA256(A0, h1p, 0, w, lane);
  stB256(B0, WaI + (size_t)(nb*2)*98304, 0, w, lane);
  __syncthreads();
  #pragma unroll 1
  for (int pass=0; pass<2; ++pass){
    const short* Wimg = pass ? (WbI + (size_t)(nb*2)*98304) : (WaI + (size_t)(nb*2)*98304);
    const u16* Ap = pass ? h2p : h1p;
    #pragma unroll
    for (int ks2=0; ks2<12; ++ks2){
      const short* Ac = (ks2&1)? A1 : A0;
      const short* Bc = (ks2&1)? B1 : B0;
      short* An = (ks2&1)? A0 : A1;
      short* Bn = (ks2&1)? B0 : B1;
      if (ks2<11){
        stA256(An, Ap, ks2+1, w, lane);
        stB256(Bn, Wimg + (size_t)((ks2+1)>>1)*16384, (ks2+1)&1, w, lane);
      } else if (pass==0){
        stA256(An, h2p, 0, w, lane);
        stB256(Bn, WbI + (size_t)(nb*2)*98304, 0, w, lane);
      }
      #pragma unroll
      for (int ks=0; ks<2; ++ks){
        bf16x8 a[8], b[4];
        #pragma unroll
        for (int mf=0; mf<8; ++mf){ int r = wm*128+mf*16+l15; a[mf] = *(const bf16x8*)&Ac[r*64 + (((ks*4+g)^(r&7))<<3)]; }
        #pragma unroll
        for (int nf=0; nf<4; ++nf){ int r = wn*64+nf*16+l15; b[nf] = *(const bf16x8*)&Bc[r*64 + (((ks*4+g)^(r&7))<<3)]; }
        #pragma unroll
        for (int mf=0; mf<8; ++mf)
          #pragma unroll
          for (int nf=0; nf<4; ++nf)
            acc[mf][nf] = MFMA(a[mf], b[nf], acc[mf][nf]);
      }
      __syncthreads();
    }
  }
  // epilogue: bias+rel, relu, dot Wg2 -> per-row partials
  float gp[8][4];
  #pragma unroll
  for (int mf=0; mf<8; ++mf)
    #pragma unroll
    for (int r=0; r<4; ++r) gp[mf][r]=0.f;
  #pragma unroll
  for (int mf=0; mf<8; ++mf)
    #pragma unroll
    for (int nf=0; nf<4; ++nf)
      #pragma unroll
      for (int r=0; r<4; ++r){
        int col = nb*256 + wn*64 + nf*16 + l15;
        gp[mf][r] += fmaxf(acc[mf][nf][r] + bg1[col] + relb*wg1c[col], 0.f) * Wg2[col];
      }
  #pragma unroll
  for (int mf=0; mf<8; ++mf)
    #pragma unroll
    for (int r=0; r<4; ++r){
      float v = gp[mf][r];
      v += __shfl_xor(v,1); v += __shfl_xor(v,2); v += __shfl_xor(v,4); v += __shfl_xor(v,8);
      gp[mf][r] = v;
    }
  float* gred = (float*)lds;   // 4 x 256 floats; A0 dead after final barrier
  if (l15 == 0)
    #pragma unroll
    for (int mf=0; mf<8; ++mf)
      #pragma unroll
      for (int r=0; r<4; ++r)
        gred[wn*256 + wm*128 + mf*16 + g*4 + r] = gp[mf][r];
  __syncthreads();
  if (tid < 256)
    gpart[(size_t)nb*65536 + t0 + tid] = gred[tid] + gred[256+tid] + gred[512+tid] + gred[768+tid];
}

// ---------------- lnk: out = LN(hs + sigmoid(sum gpart + bg2)*ctxo) ----------------
__global__ __launch_bounds__(256) void lnk(const float* __restrict__ gpart,
    const float* __restrict__ bg2, const float* __restrict__ lng,
    const float* __restrict__ lnb, float* outp){
  const int tid = threadIdx.x, lane = tid & 63, w = tid >> 6;
  u16* holes = (u16*)outp;
  const float bg2v = bg2[0];
  #pragma unroll 1
  for (int i=0; i<8; ++i){
    int row = blockIdx.x*32 + w*8 + i;
    float gsum = bg2v;
    #pragma unroll
    for (int nb2=0; nb2<3; ++nb2) gsum += gpart[(size_t)nb2*65536 + row];
    float gg = 1.f/(1.f + __expf(-gsum));
    int c1 = lane, c2 = 64 + (lane & 31);
    size_t rb = (size_t)row*1536;
    bf16x8 hv1 = __builtin_nontemporal_load((const bf16x8*)&holes[rb + pch(c1,row)*8]);
    bf16x8 ov1 = __builtin_nontemporal_load((const bf16x8*)&holes[rb + 768 + pch(c1,row)*8]);
    bf16x8 hv2 = __builtin_nontemporal_load((const bf16x8*)&holes[rb + pch(c2,row)*8]);
    bf16x8 ov2 = __builtin_nontemporal_load((const bf16x8*)&holes[rb + 768 + pch(c2,row)*8]);
    float x1[8], x2[8];
    float sum=0.f, sq=0.f;
    #pragma unroll
    for (int j=0;j<8;++j){ float x = bf2f(hv1[j]) + gg*bf2f(ov1[j]); x1[j]=x; sum+=x; sq+=x*x; }
    if (lane < 32){
      #pragma unroll
      for (int j=0;j<8;++j){ float x = bf2f(hv2[j]) + gg*bf2f(ov2[j]); x2[j]=x; sum+=x; sq+=x*x; }
    }
    #pragma unroll
    for (int m=1; m<64; m<<=1){ sum += __shfl_xor(sum,m); sq += __shfl_xor(sq,m); }
    float mu = sum * (1.f/768.f);
    float var = sq * (1.f/768.f) - mu*mu;
    float rs = rsqrtf(var + 1e-5f);
    {
      f32x4 ga = *(const f32x4*)&lng[c1*8], gb = *(const f32x4*)&lng[c1*8+4];
      f32x4 ba = *(const f32x4*)&lnb[c1*8], bb = *(const f32x4*)&lnb[c1*8+4];
      f32x4 o0, o1;
      #pragma unroll
      for (int j=0;j<4;++j){ o0[j] = (x1[j]-mu)*rs*ga[j]+ba[j]; o1[j] = (x1[4+j]-mu)*rs*gb[j]+bb[j]; }
      __builtin_nontemporal_store(o0, (f32x4*)&outp[(size_t)row*768 + c1*8]);
      __builtin_nontemporal_store(o1, (f32x4*)&outp[(size_t)row*768 + c1*8 + 4]);
    }
    if (lane < 32){
      f32x4 ga = *(const f32x4*)&lng[c2*8], gb = *(const f32x4*)&lng[c2*8+4];
      f32x4 ba = *(const f32x4*)&lnb[c2*8], bb = *(const f32x4*)&lnb[c2*8+4];
      f32x4 o0, o1;
      #pragma unroll
      for (int j=0;j<4;++j){ o0[j] = (x2[j]-mu)*rs*ga[j]+ba[j]; o1[j] = (x2[4+j]-mu)*rs*gb[j]+bb[j]; }
      __builtin_nontemporal_store(o0, (f32x4*)&outp[(size_t)row*768 + c2*8]);
      __builtin_nontemporal_store(o1, (f32x4*)&outp[(size_t)row*768 + c2*8 + 4]);
    }
  }
}

extern "C" void kernel_launch(void* const* d_in, const int* in_sizes, int n_in,
                              void* d_out, int out_size, void* d_ws, size_t ws_size,
                              hipStream_t stream) {
  (void)in_sizes; (void)n_in; (void)out_size; (void)ws_size;
  const float* hs  = (const float*)d_in[0];
  const float* ce  = (const float*)d_in[1];
  const float* Wq  = (const float*)d_in[2];
  const float* bq  = (const float*)d_in[3];
  const float* Wk  = (const float*)d_in[4];
  const float* bk  = (const float*)d_in[5];
  const float* Wv  = (const float*)d_in[6];
  const float* bv  = (const float*)d_in[7];
  const float* Wo  = (const float*)d_in[8];
  const float* bo  = (const float*)d_in[9];
  const float* Wg1 = (const float*)d_in[10];
  const float* bg1 = (const float*)d_in[11];
  const float* Wg2 = (const float*)d_in[12];
  const float* bg2 = (const float*)d_in[13];
  const float* lng = (const float*)d_in[14];
  const float* lnb = (const float*)d_in[15];
  char* ws = (char*)d_ws;
  short* WeffI = (short*)(ws + 0);
  short* VWoI  = (short*)(ws + 1179648);
  short* WaI   = (short*)(ws + 2359296);
  short* WbI   = (short*)(ws + 3538944);
  short* Kc    = (short*)(ws + 4718592);
  short* VT    = (short*)(ws + 4816896);
  float* wg1c  = (float*)(ws + 4915200);
  float* cp    = (float*)(ws + 4918272);
  float* rel   = (float*)(ws + 4970496);
  float* tpp   = (float*)(ws + 4970752);
  float* gpart = (float*)(ws + 4970752);   // aliases tpp (dead by gate_mm); 3*65536*4
  float* sbias = (float*)(ws + 6543616);
  float* outp  = (float*)d_out;

  prep_kv  <<<96,  256, 0, stream>>>(ce, Wk, bk, Wv, bv, Kc, VT);
  prep_w   <<<72,  256, 0, stream>>>(Wg1, WaI, WbI);
  prep_misc<<<17,  256, 0, stream>>>(Wg1, ce, bq, Kc, wg1c, cp, sbias);
  prep_eff <<<48,  256, 0, stream>>>(Wq, Kc, WeffI);
  prep_vwo <<<48,  256, 0, stream>>>(Wo, VT, VWoI);
  prep_hs  <<<512, 384, 0, stream>>>(hs, outp, tpp);
  pool23   <<<16,  256, 0, stream>>>(tpp, cp, rel);
  gs       <<<2048,256, 0, stream>>>(WeffI, sbias, outp);
  gvwo     <<<1024,256, 0, stream>>>(VWoI, bo, outp);
  hipFuncSetAttribute(reinterpret_cast<const void*>(gate_mm),
                      hipFuncAttributeMaxDynamicSharedMemorySize, 131072);
  gate_mm  <<<768, 512, 131072, stream>>>(WaI, WbI, bg1, wg1c, Wg2, rel, gpart, outp);
  lnk      <<<2048,256, 0, stream>>>(gpart, bg2, lng, lnb, outp);
}

// Round 14
// 491.124 us; speedup vs baseline: 1.6696x; 1.0194x over previous
//
#include <hip/hip_runtime.h>

typedef __attribute__((ext_vector_type(8))) short bf16x8;
typedef __attribute__((ext_vector_type(4))) float f32x4;
typedef unsigned short u16;

#define MFMA(a,b,c) __builtin_amdgcn_mfma_f32_16x16x32_bf16((a),(b),(c),0,0,0)

__device__ __forceinline__ short f2bf(float f){
  union { float f; unsigned u; } v; v.f = f;
  unsigned r = v.u + 0x7FFFu + ((v.u >> 16) & 1u);
  return (short)(r >> 16);
}
__device__ __forceinline__ float bf2f(short s){
  union { unsigned u; float f; } v; v.u = ((unsigned)(unsigned short)s) << 16; return v.f;
}
__device__ __forceinline__ bf16x8 pack8(f32x4 x, f32x4 y){
  bf16x8 r;
  r[0]=f2bf(x[0]); r[1]=f2bf(x[1]); r[2]=f2bf(x[2]); r[3]=f2bf(x[3]);
  r[4]=f2bf(y[0]); r[5]=f2bf(y[1]); r[6]=f2bf(y[2]); r[7]=f2bf(y[3]);
  return r;
}
// hole swizzle: physical 16B-chunk index for logical chunk c of row
__device__ __forceinline__ int pch(int c, int row){ return (c & ~7) | ((c & 7) ^ (row & 7)); }

__device__ __forceinline__ void gload16(void* lp, const void* gp){
  __builtin_amdgcn_global_load_lds((const __attribute__((address_space(1))) unsigned*)gp,
                                   (__attribute__((address_space(3))) unsigned*)lp, 16, 0, 0);
}
// ---- 256-thread staging helpers (16KB) ----
__device__ __forceinline__ void stWB(short* buf, const short* img, int half, int w, int lane){
  const char* gp = (const char*)img;
  #pragma unroll
  for (int it=0; it<4; ++it){
    int id = it*256 + w*64 + lane; int r = id>>3, c = id&7;
    gload16((char*)buf + it*4096 + w*1024, gp + r*256 + half*128 + c*16);
  }
}
// ---- 512-thread staging helpers (32KB: 256 rows x 8 chunks) ----
__device__ __forceinline__ void stA256(short* buf, const u16* rowb, int kstep, int w, int lane){
  int tid = w*64 + lane;
  #pragma unroll
  for (int it=0; it<4; ++it){
    int id = it*512 + tid; int r = id>>3, c = id&7;
    gload16((char*)buf + it*8192 + w*1024, rowb + (size_t)r*1536 + (kstep*8 + c)*8);
  }
}
// img points at block (jt0*6+kt); rows 128.. come from block (jt0+1)*6+kt (stride 98304 shorts)
__device__ __forceinline__ void stB256(short* buf, const short* img, int half, int w, int lane){
  int tid = w*64 + lane;
  #pragma unroll
  for (int it=0; it<4; ++it){
    int id = it*512 + tid; int r = id>>3, c = id&7;
    gload16((char*)buf + it*8192 + w*1024,
            img + (size_t)(r>>7)*98304 + (size_t)(r&127)*128 + half*64 + c*8);
  }
}

// ---------------- prep1: blocks 0-95 = KV projection; 96-167 = gate-weight images ----------------
__global__ __launch_bounds__(256) void prep1(const float* __restrict__ ce,
    const float* __restrict__ Wk, const float* __restrict__ bk,
    const float* __restrict__ Wv, const float* __restrict__ bv,
    const float* __restrict__ Wg1, short* __restrict__ Kc, short* __restrict__ VT,
    short* __restrict__ WaI, short* __restrict__ WbI){
  __shared__ float smemf[8704];   // 34816B: kv uses 24KB (sh), w uses 34816B (lt)
  int b = blockIdx.x, tid = threadIdx.x;
  if (b < 96){
    float* sh = smemf;                       // [8][768]
    int jt = b / 8, cg = b % 8;
    int j = jt*64 + (tid & 63);
    int cl = tid >> 6;
    for (int i = tid; i < 8*768; i += 256){
      int c2 = i / 768; int h = i - c2*768;
      sh[c2*768 + h] = ce[(size_t)(cg*8+c2)*768 + h];
    }
    __syncthreads();
    float aK0=0.f, aV0=0.f, aK1=0.f, aV1=0.f;
    #pragma unroll 4
    for (int h=0; h<768; ++h){
      float wk = Wk[(size_t)h*768 + j];
      float wv = Wv[(size_t)h*768 + j];
      float x0 = sh[(cl*2)*768 + h], x1 = sh[(cl*2+1)*768 + h];
      aK0 += x0*wk; aV0 += x0*wv;
      aK1 += x1*wk; aV1 += x1*wv;
    }
    float bkj = bk[j], bvj = bv[j];
    int c0 = cg*8 + cl*2;
    Kc[(size_t)c0*768 + j]     = f2bf(aK0 + bkj);
    Kc[(size_t)(c0+1)*768 + j] = f2bf(aK1 + bkj);
    VT[(size_t)j*64 + c0]      = f2bf(aV0 + bvj);
    VT[(size_t)j*64 + c0+1]    = f2bf(aV1 + bvj);
  } else {
    short* lt = (short*)smemf;               // [128][136]
    int blk = b - 96;                        // 72 = 2 mats * 6 kt * 6 jt
    int mat = blk / 36, t = blk % 36, kt = t / 6, jt = t % 6;
    const float* src = (mat==0)? Wg1 : (Wg1 + (size_t)768*768);
    short* dst = (mat==0)? WaI : WbI;
    #pragma unroll
    for (int it=0; it<16; ++it){
      int kl = it*8 + (tid>>5);
      int jl = (tid&31)*4;
      f32x4 v = *(const f32x4*)&src[(size_t)(kt*128+kl)*768 + jt*128 + jl];
      lt[(jl+0)*136+kl]=f2bf(v[0]); lt[(jl+1)*136+kl]=f2bf(v[1]);
      lt[(jl+2)*136+kl]=f2bf(v[2]); lt[(jl+3)*136+kl]=f2bf(v[3]);
    }
    __syncthreads();
    size_t base = (size_t)(jt*6 + kt)*16384;
    #pragma unroll
    for (int cc=0; cc<8; ++cc){
      int ci = cc*256 + tid;
      int jl = ci >> 4, sc = ci & 15;
      int kkb = ((sc ^ (jl & 7)) << 3);
      bf16x8 v = *(const bf16x8*)&lt[jl*136 + kkb];
      *(bf16x8*)&dst[base + (size_t)jl*128 + sc*8] = v;
    }
  }
}

// ---------------- prep2: 0-16 misc; 17-64 Weff image; 65-112 VWo image ----------------
__global__ __launch_bounds__(256) void prep2(const float* __restrict__ Wg1,
    const float* __restrict__ ce, const float* __restrict__ bq,
    const short* __restrict__ Kc, const float* __restrict__ Wq,
    const float* __restrict__ Wo, const short* __restrict__ VT,
    float* __restrict__ wg1c, float* __restrict__ cp, float* __restrict__ sbias,
    short* __restrict__ WeffI, short* __restrict__ VWoI){
  __shared__ float smemf[9984];   // 39936B
  int b = blockIdx.x, tid = threadIdx.x;
  if (b < 17){
    float* red = smemf;  // [4][64]
    if (b < 12){
      int j = b*64 + (tid & 63);
      int kq = tid >> 6;
      float s = 0.f;
      for (int r=0; r<192; ++r)
        s += Wg1[(size_t)(1536 + kq*192 + r)*768 + j];
      red[kq*64 + (tid&63)] = s;
      __syncthreads();
      if (tid < 64) wg1c[b*64+tid] = red[tid]+red[64+tid]+red[128+tid]+red[192+tid];
    } else if (b < 15){
      int h = (b-12)*256 + tid;
      float s = 0.f;
      #pragma unroll
      for (int c2=0; c2<64; ++c2) s += ce[(size_t)c2*768 + h];
      cp[h] = s * (1.f/64.f);
    } else {
      int hc = (b-15)*256 + tid;
      int h = hc >> 6, c = hc & 63;
      float s = 0.f;
      #pragma unroll
      for (int j=0; j<96; ++j)
        s += bq[h*96+j] * bf2f(Kc[(size_t)c*768 + h*96 + j]);
      sbias[hc] = s * 0.10206207262f;
    }
  } else if (b < 65){
    short* KA = (short*)smemf;           // [64][104]
    short* WB = KA + 6656;               // [128][104]
    int e = b - 17;
    int h = e / 6, kt = e % 6;
    const int lane = tid & 63, w = tid >> 6, l15 = lane & 15, g = lane >> 4;
    #pragma unroll
    for (int it=0; it<3; ++it){
      int i = it*256 + tid;
      int c = i / 12, cb = i % 12;
      *(bf16x8*)&KA[c*104 + cb*8] = *(const bf16x8*)&Kc[(size_t)c*768 + h*96 + cb*8];
    }
    #pragma unroll
    for (int it=0; it<12; ++it){
      int i = it*256 + tid;
      int d = i / 24, q = i % 24;
      f32x4 v = *(const f32x4*)&Wq[(size_t)(kt*128+d)*768 + h*96 + q*4];
      WB[d*104 + q*4+0]=f2bf(v[0]); WB[d*104 + q*4+1]=f2bf(v[1]);
      WB[d*104 + q*4+2]=f2bf(v[2]); WB[d*104 + q*4+3]=f2bf(v[3]);
    }
    __syncthreads();
    f32x4 acc[4][2];
    #pragma unroll
    for (int i=0;i<4;++i){ acc[i][0]=(f32x4){0,0,0,0}; acc[i][1]=(f32x4){0,0,0,0}; }
    #pragma unroll
    for (int ks=0; ks<3; ++ks){
      bf16x8 a[4], bb[2];
      #pragma unroll
      for (int mf=0; mf<4; ++mf) a[mf] = *(const bf16x8*)&KA[(mf*16+l15)*104 + ks*32+g*8];
      #pragma unroll
      for (int nf=0; nf<2; ++nf) bb[nf] = *(const bf16x8*)&WB[(w*32+nf*16+l15)*104 + ks*32+g*8];
      #pragma unroll
      for (int mf=0; mf<4; ++mf)
        #pragma unroll
        for (int nf=0; nf<2; ++nf)
          acc[mf][nf] = MFMA(a[mf], bb[nf], acc[mf][nf]);
    }
    size_t base = (size_t)((h>>1)*6 + kt)*16384;
    #pragma unroll
    for (int mf=0; mf<4; ++mf)
      #pragma unroll
      for (int nf=0; nf<2; ++nf)
        #pragma unroll
        for (int r=0; r<4; ++r){
          int c = mf*16 + g*4 + r;
          int d = w*32 + nf*16 + l15;
          int hcl = (h&1)*64 + c;
          WeffI[base + (size_t)hcl*128 + (((d>>3)^(hcl&7))<<3) + (d&7)] = f2bf(acc[mf][nf][r] * 0.10206207262f);
        }
  } else {
    short* WoT = (short*)smemf;          // [128][104]
    short* VA  = WoT + 13312;            // [64][104]
    int e = b - 65;
    int h = e / 6, dt = e % 6;
    const int lane = tid & 63, w = tid >> 6, l15 = lane & 15, g = lane >> 4;
    #pragma unroll
    for (int it=0; it<12; ++it){
      int i = it*256 + tid;
      int j = i / 32, qd = i % 32;
      f32x4 v = *(const f32x4*)&Wo[(size_t)(h*96+j)*768 + dt*128 + qd*4];
      WoT[(qd*4+0)*104 + j]=f2bf(v[0]); WoT[(qd*4+1)*104 + j]=f2bf(v[1]);
      WoT[(qd*4+2)*104 + j]=f2bf(v[2]); WoT[(qd*4+3)*104 + j]=f2bf(v[3]);
    }
    #pragma unroll
    for (int it=0; it<3; ++it){
      int i = it*256 + tid;
      int j = i / 8, cb = i % 8;
      bf16x8 v = *(const bf16x8*)&VT[(size_t)(h*96+j)*64 + cb*8];
      #pragma unroll
      for (int x=0; x<8; ++x) VA[(cb*8+x)*104 + j] = v[x];
    }
    __syncthreads();
    f32x4 acc[2][4];
    #pragma unroll
    for (int i=0;i<2;++i)
      #pragma unroll
      for (int j=0;j<4;++j) acc[i][j]=(f32x4){0,0,0,0};
    #pragma unroll
    for (int ks=0; ks<3; ++ks){
      bf16x8 a[2], bb[4];
      #pragma unroll
      for (int mf=0; mf<2; ++mf) a[mf] = *(const bf16x8*)&WoT[(w*32+mf*16+l15)*104 + ks*32+g*8];
      #pragma unroll
      for (int nf=0; nf<4; ++nf) bb[nf] = *(const bf16x8*)&VA[(nf*16+l15)*104 + ks*32+g*8];
      #pragma unroll
      for (int mf=0; mf<2; ++mf)
        #pragma unroll
        for (int nf=0; nf<4; ++nf)
          acc[mf][nf] = MFMA(a[mf], bb[nf], acc[mf][nf]);
    }
    size_t base = (size_t)(dt*4 + (h>>1))*16384;
    #pragma unroll
    for (int mf=0; mf<2; ++mf)
      #pragma unroll
      for (int nf=0; nf<4; ++nf)
        #pragma unroll
        for (int r=0; r<4; ++r){
          int d = w*32 + mf*16 + g*4 + r;
          int c = nf*16 + l15;
          int hcl = (h&1)*64 + c;
          VWoI[base + (size_t)d*128 + (((hcl>>3)^(d&7))<<3) + (hcl&7)] = f2bf(acc[mf][nf][r]);
        }
  }
}

// hs f32 -> bf16 pre-swizzled hole1 + partial column sums. 512 blocks x 384 thr.
__global__ __launch_bounds__(384) void prep_hs(const float* __restrict__ hs,
                                               float* __restrict__ outp, float* __restrict__ tpp){
  __shared__ float csum[4][768];
  int tid = threadIdx.x;
  int c = tid % 96, rg = tid / 96;
  size_t r0 = (size_t)blockIdx.x * 128;
  u16* holes = (u16*)outp;
  float s[8];
  #pragma unroll
  for (int j=0;j<8;++j) s[j]=0.f;
  #pragma unroll 4
  for (int i=0; i<32; ++i){
    size_t row = r0 + rg*32 + i;
    const float* p = hs + row*768 + c*8;
    f32x4 x = __builtin_nontemporal_load((const f32x4*)p);
    f32x4 y = __builtin_nontemporal_load((const f32x4*)(p+4));
    *(bf16x8*)&holes[row*1536 + pch(c,(int)row)*8] = pack8(x,y);
    #pragma unroll
    for (int j=0;j<4;++j){ s[j]+=x[j]; s[4+j]+=y[j]; }
  }
  #pragma unroll
  for (int j=0;j<8;++j) csum[rg][c*8+j] = s[j];
  __syncthreads();
  for (int cc=tid; cc<768; cc+=384)
    tpp[(size_t)blockIdx.x*768 + cc] = csum[0][cc]+csum[1][cc]+csum[2][cc]+csum[3][cc];
}

// merged pool2+pool3: 16 blocks x 256 thr
__global__ void pool23(const float* __restrict__ tpp, const float* __restrict__ cp,
                       float* __restrict__ rel){
  int b = blockIdx.x;
  float a=0.f, n1=0.f, n2=0.f;
  for (int h = threadIdx.x; h < 768; h += 256){
    float s = 0.f;
    #pragma unroll
    for (int k=0; k<32; ++k) s += tpp[((size_t)b*32 + k)*768 + h];
    s *= (1.f/4096.f);
    float c = cp[h];
    a += s*c; n1 += s*s; n2 += c*c;
  }
  #pragma unroll
  for (int m=1; m<64; m<<=1){ a+=__shfl_xor(a,m); n1+=__shfl_xor(n1,m); n2+=__shfl_xor(n2,m); }
  __shared__ float r3[3][4];
  int w = threadIdx.x >> 6;
  if ((threadIdx.x & 63) == 0){ r3[0][w]=a; r3[1][w]=n1; r3[2][w]=n2; }
  __syncthreads();
  if (threadIdx.x == 0){
    float A = r3[0][0]+r3[0][1]+r3[0][2]+r3[0][3];
    float N1= r3[1][0]+r3[1][1]+r3[1][2]+r3[1][3];
    float N2= r3[2][0]+r3[2][1]+r3[2][2]+r3[2][3];
    rel[b] = A / (fmaxf(sqrtf(N1),1e-8f) * fmaxf(sqrtf(N2),1e-8f));
  }
}

// ---------------- gs256: S = hs @ Weff + sbias, per-head softmax fused -> attn bf16 in hole2 ----------------
// gate_mm skeleton: 256x256-ish tile (M=256, N=256), 512 thr, 8 waves (2M x 4N), K=768
__global__ void __launch_bounds__(512)
__attribute__((amdgpu_waves_per_eu(2, 2))) gs256(const short* __restrict__ WeffI,
    const float* __restrict__ sbias, float* outp){
  extern __shared__ char lds[];
  short* A0 = (short*)lds;                 // 32KB: 256 rows x 64 shorts
  short* A1 = (short*)(lds + 32768);
  short* B0 = (short*)(lds + 65536);
  short* B1 = (short*)(lds + 98304);
  const int tid = threadIdx.x, lane = tid & 63, w = tid >> 6;
  const int l15 = lane & 15, g = lane >> 4;
  const int bid = blockIdx.x;              // 512 = 256 mt x 2 nb
  const int nb = (bid >> 3) & 1, mt = (bid >> 4)*8 + (bid & 7);
  const int wm = w & 1, wn = w >> 1;       // wave tile: 128M x 64N (one head)
  const size_t t0 = (size_t)mt*256;
  u16* holes = (u16*)outp;
  const u16* h1p = holes + t0*1536;
  const short* Wimg = WeffI + (size_t)(nb*2)*98304;
  f32x4 acc[8][4];
  #pragma unroll
  for (int i=0;i<8;++i)
    #pragma unroll
    for (int j=0;j<4;++j) acc[i][j]=(f32x4){0.f,0.f,0.f,0.f};
  stA256(A0, h1p, 0, w, lane);
  stB256(B0, Wimg, 0, w, lane);
  __syncthreads();
  #pragma unroll
  for (int ks2=0; ks2<12; ++ks2){
    const short* Ac = (ks2&1)? A1 : A0;
    const short* Bc = (ks2&1)? B1 : B0;
    short* An = (ks2&1)? A0 : A1;
    short* Bn = (ks2&1)? B0 : B1;
    if (ks2<11){
      stA256(An, h1p, ks2+1, w, lane);
      stB256(Bn, Wimg + (size_t)((ks2+1)>>1)*16384, (ks2+1)&1, w, lane);
    }
    #pragma unroll
    for (int ks=0; ks<2; ++ks){
      bf16x8 a[8], b[4];
      #pragma unroll
      for (int mf=0; mf<8; ++mf){ int r = wm*128+mf*16+l15; a[mf] = *(const bf16x8*)&Ac[r*64 + (((ks*4+g)^(r&7))<<3)]; }
      #pragma unroll
      for (int nf=0; nf<4; ++nf){ int r = wn*64+nf*16+l15; b[nf] = *(const bf16x8*)&Bc[r*64 + (((ks*4+g)^(r&7))<<3)]; }
      #pragma unroll
      for (int mf=0; mf<8; ++mf)
        #pragma unroll
        for (int nf=0; nf<4; ++nf)
          acc[mf][nf] = MFMA(a[mf], b[nf], acc[mf][nf]);
    }
    __syncthreads();
  }
  // epilogue: +sbias, per-head softmax (wave n-span == one head), write attn bf16
  #pragma unroll
  for (int mf=0; mf<8; ++mf)
    #pragma unroll
    for (int r=0; r<4; ++r){
      float v[4];
      #pragma unroll
      for (int nf=0; nf<4; ++nf)
        v[nf] = acc[mf][nf][r] + sbias[nb*256 + wn*64 + nf*16 + l15];
      float m = fmaxf(fmaxf(v[0],v[1]), fmaxf(v[2],v[3]));
      m = fmaxf(m,__shfl_xor(m,1)); m = fmaxf(m,__shfl_xor(m,2));
      m = fmaxf(m,__shfl_xor(m,4)); m = fmaxf(m,__shfl_xor(m,8));
      float e[4]; float s = 0.f;
      #pragma unroll
      for (int nf=0; nf<4; ++nf){ e[nf] = __expf(v[nf]-m); s += e[nf]; }
      s += __shfl_xor(s,1); s += __shfl_xor(s,2); s += __shfl_xor(s,4); s += __shfl_xor(s,8);
      float inv = 1.f/s;
      int grow = wm*128 + mf*16 + g*4 + r;
      #pragma unroll
      for (int nf=0; nf<4; ++nf){
        int col = nb*256 + wn*64 + nf*16 + l15;
        holes[(t0+grow)*1536 + 768 + pch(col>>3, grow)*8 + (col&7)] = (u16)f2bf(e[nf]*inv);
      }
    }
}

// ---------------- gvwo: ctxo = attn @ VWo + bo -> hole2[0,768); attn_avg fused from regs ----------------
__global__ __launch_bounds__(256) void gvwo(const short* __restrict__ VWoI,
                                            const float* __restrict__ bo, float* outp){
  __shared__ short B0[8192], B1[8192];
  const int tid = threadIdx.x, lane = tid & 63, w = tid >> 6;
  const int l15 = lane & 15, g = lane >> 4;
  const size_t t0 = (size_t)blockIdx.x * 64;
  const int arow = w*16 + l15;
  const int drow = w*16 + g*4;
  u16* holes = (u16*)outp;
  bf16x8 af[16];
  #pragma unroll
  for (int kk=0; kk<16; ++kk){
    int kc = kk*4 + g;
    af[kk] = *(const bf16x8*)&holes[(t0+arow)*1536 + 768 + pch(kc, arow)*8];
  }
  stWB(B0, VWoI, 0, w, lane);
  {
    float s0[8], s1[8];
    #pragma unroll
    for (int j=0;j<8;++j){ s0[j]=0.f; s1[j]=0.f; }
    #pragma unroll
    for (int kk=0; kk<16; kk+=2)
      #pragma unroll
      for (int j=0;j<8;++j) s0[j] += bf2f(af[kk][j]);
    #pragma unroll
    for (int kk=1; kk<16; kk+=2)
      #pragma unroll
      for (int j=0;j<8;++j) s1[j] += bf2f(af[kk][j]);
    float* ap = &outp[(size_t)50331648 + (size_t)(t0+arow)*64];
    f32x4 o;
    #pragma unroll
    for (int j=0;j<4;++j) o[j] = s0[j]*0.125f;
    __builtin_nontemporal_store(o, (f32x4*)(ap + g*8));
    #pragma unroll
    for (int j=0;j<4;++j) o[j] = s0[4+j]*0.125f;
    __builtin_nontemporal_store(o, (f32x4*)(ap + g*8 + 4));
    #pragma unroll
    for (int j=0;j<4;++j) o[j] = s1[j]*0.125f;
    __builtin_nontemporal_store(o, (f32x4*)(ap + (4+g)*8));
    #pragma unroll
    for (int j=0;j<4;++j) o[j] = s1[4+j]*0.125f;
    __builtin_nontemporal_store(o, (f32x4*)(ap + (4+g)*8 + 4));
  }
  __syncthreads();
  #pragma unroll 1
  for (int nb=0; nb<6; ++nb){
    f32x4 acc[8];
    #pragma unroll
    for (int i=0;i<8;++i) acc[i]=(f32x4){0.f,0.f,0.f,0.f};
    #pragma unroll
    for (int ks2=0; ks2<8; ++ks2){
      const short* Bc = (ks2&1)? B1 : B0;
      short* Bn = (ks2&1)? B0 : B1;
      if (ks2<7)       stWB(Bn, VWoI + (size_t)(nb*4 + ((ks2+1)>>1))*16384, (ks2+1)&1, w, lane);
      else if (nb<5)   stWB(Bn, VWoI + (size_t)((nb+1)*4)*16384, 0, w, lane);
      #pragma unroll
      for (int ks=0; ks<2; ++ks){
        bf16x8 a = af[ks2*2 + ks];
        #pragma unroll
        for (int nf=0; nf<8; ++nf){
          int br = nf*16 + l15;
          bf16x8 b = *(const bf16x8*)&Bc[br*64 + (((ks*4+g)^(br&7))<<3)];
          acc[nf] = MFMA(a, b, acc[nf]);
        }
      }
      __syncthreads();
    }
    #pragma unroll
    for (int nf=0; nf<8; ++nf)
      #pragma unroll
      for (int r=0; r<4; ++r){
        int row = drow + r;
        int col = nb*128 + nf*16 + l15;
        float v = acc[nf][r] + bo[col];
        holes[(t0+row)*1536 + 768 + pch(col>>3, row)*8 + (col&7)] = (u16)f2bf(v);
      }
  }
}

// ---------------- gate_mm: 256x256 tile, 512 thr, 8 waves (2M x 4N), K=1536 -> gpart (3 nb) ----------------
__global__ void __launch_bounds__(512)
__attribute__((amdgpu_waves_per_eu(2, 2))) gate_mm(const short* __restrict__ WaI,
    const short* __restrict__ WbI, const float* __restrict__ bg1,
    const float* __restrict__ wg1c, const float* __restrict__ Wg2,
    const float* __restrict__ rel, float* __restrict__ gpart, float* outp){
  extern __shared__ char lds[];
  short* A0 = (short*)lds;                 // 32KB: 256 rows x 64 shorts
  short* A1 = (short*)(lds + 32768);
  short* B0 = (short*)(lds + 65536);
  short* B1 = (short*)(lds + 98304);
  const int tid = threadIdx.x, lane = tid & 63, w = tid >> 6;
  const int l15 = lane & 15, g = lane >> 4;
  const int bid = blockIdx.x;              // 768 = 256 mt x 3 nb
  const int nb = (bid >> 3) % 3, mt = (bid/24)*8 + (bid & 7);
  const int wm = w & 1, wn = w >> 1;       // wave tile: 128M x 64N
  const size_t t0 = (size_t)mt*256;
  const float relb = rel[t0 >> 12];
  u16* holes = (u16*)outp;
  const u16* h1p = holes + t0*1536;
  const u16* h2p = h1p + 768;
  f32x4 acc[8][4];
  #pragma unroll
  for (int i=0;i<8;++i)
    #pragma unroll
    for (int j=0;j<4;++j) acc[i][j]=(f32x4){0.f,0.f,0.f,0.f};
  stA256(A0, h1p, 0, w, lane);
  stB256(B0, WaI + (size_t)(nb*2)*98304, 0, w, lane);
  __syncthreads();
  #pragma unroll 1
  for (int pass=0; pass<2; ++pass){
    const short* Wimg = pass ? (WbI + (size_t)(nb*2)*98304) : (WaI + (size_t)(nb*2)*98304);
    const u16* Ap = pass ? h2p : h1p;
    #pragma unroll
    for (int ks2=0; ks2<12; ++ks2){
      const short* Ac = (ks2&1)? A1 : A0;
      const short* Bc = (ks2&1)? B1 : B0;
      short* An = (ks2&1)? A0 : A1;
      short* Bn = (ks2&1)? B0 : B1;
      if (ks2<11){
        stA256(An, Ap, ks2+1, w, lane);
        stB256(Bn, Wimg + (size_t)((ks2+1)>>1)*16384, (ks2+1)&1, w, lane);
      } else if (pass==0){
        stA256(An, h2p, 0, w, lane);
        stB256(Bn, WbI + (size_t)(nb*2)*98304, 0, w, lane);
      }
      #pragma unroll
      for (int ks=0; ks<2; ++ks){
        bf16x8 a[8], b[4];
        #pragma unroll
        for (int mf=0; mf<8; ++mf){ int r = wm*128+mf*16+l15; a[mf] = *(const bf16x8*)&Ac[r*64 + (((ks*4+g)^(r&7))<<3)]; }
        #pragma unroll
        for (int nf=0; nf<4; ++nf){ int r = wn*64+nf*16+l15; b[nf] = *(const bf16x8*)&Bc[r*64 + (((ks*4+g)^(r&7))<<3)]; }
        #pragma unroll
        for (int mf=0; mf<8; ++mf)
          #pragma unroll
          for (int nf=0; nf<4; ++nf)
            acc[mf][nf] = MFMA(a[mf], b[nf], acc[mf][nf]);
      }
      __syncthreads();
    }
  }
  // epilogue: bias+rel, relu, dot Wg2 -> per-row partials
  float gp[8][4];
  #pragma unroll
  for (int mf=0; mf<8; ++mf)
    #pragma unroll
    for (int r=0; r<4; ++r) gp[mf][r]=0.f;
  #pragma unroll
  for (int mf=0; mf<8; ++mf)
    #pragma unroll
    for (int nf=0; nf<4; ++nf)
      #pragma unroll
      for (int r=0; r<4; ++r){
        int col = nb*256 + wn*64 + nf*16 + l15;
        gp[mf][r] += fmaxf(acc[mf][nf][r] + bg1[col] + relb*wg1c[col], 0.f) * Wg2[col];
      }
  #pragma unroll
  for (int mf=0; mf<8; ++mf)
    #pragma unroll
    for (int r=0; r<4; ++r){
      float v = gp[mf][r];
      v += __shfl_xor(v,1); v += __shfl_xor(v,2); v += __shfl_xor(v,4); v += __shfl_xor(v,8);
      gp[mf][r] = v;
    }
  float* gred = (float*)lds;   // 4 x 256 floats; A0 dead after final barrier
  if (l15 == 0)
    #pragma unroll
    for (int mf=0; mf<8; ++mf)
      #pragma unroll
      for (int r=0; r<4; ++r)
        gred[wn*256 + wm*128 + mf*16 + g*4 + r] = gp[mf][r];
  __syncthreads();
  if (tid < 256)
    gpart[(size_t)nb*65536 + t0 + tid] = gred[tid] + gred[256+tid] + gred[512+tid] + gred[768+tid];
}

// ---------------- lnk: out = LN(hs + sigmoid(sum gpart + bg2)*ctxo) ----------------
__global__ __launch_bounds__(256) void lnk(const float* __restrict__ gpart,
    const float* __restrict__ bg2, const float* __restrict__ lng,
    const float* __restrict__ lnb, float* outp){
  const int tid = threadIdx.x, lane = tid & 63, w = tid >> 6;
  u16* holes = (u16*)outp;
  const float bg2v = bg2[0];
  #pragma unroll 1
  for (int i=0; i<8; ++i){
    int row = blockIdx.x*32 + w*8 + i;
    float gsum = bg2v;
    #pragma unroll
    for (int nb2=0; nb2<3; ++nb2) gsum += gpart[(size_t)nb2*65536 + row];
    float gg = 1.f/(1.f + __expf(-gsum));
    int c1 = lane, c2 = 64 + (lane & 31);
    size_t rb = (size_t)row*1536;
    bf16x8 hv1 = __builtin_nontemporal_load((const bf16x8*)&holes[rb + pch(c1,row)*8]);
    bf16x8 ov1 = __builtin_nontemporal_load((const bf16x8*)&holes[rb + 768 + pch(c1,row)*8]);
    bf16x8 hv2 = __builtin_nontemporal_load((const bf16x8*)&holes[rb + pch(c2,row)*8]);
    bf16x8 ov2 = __builtin_nontemporal_load((const bf16x8*)&holes[rb + 768 + pch(c2,row)*8]);
    float x1[8], x2[8];
    float sum=0.f, sq=0.f;
    #pragma unroll
    for (int j=0;j<8;++j){ float x = bf2f(hv1[j]) + gg*bf2f(ov1[j]); x1[j]=x; sum+=x; sq+=x*x; }
    if (lane < 32){
      #pragma unroll
      for (int j=0;j<8;++j){ float x = bf2f(hv2[j]) + gg*bf2f(ov2[j]); x2[j]=x; sum+=x; sq+=x*x; }
    }
    #pragma unroll
    for (int m=1; m<64; m<<=1){ sum += __shfl_xor(sum,m); sq += __shfl_xor(sq,m); }
    float mu = sum * (1.f/768.f);
    float var = sq * (1.f/768.f) - mu*mu;
    float rs = rsqrtf(var + 1e-5f);
    {
      f32x4 ga = *(const f32x4*)&lng[c1*8], gb = *(const f32x4*)&lng[c1*8+4];
      f32x4 ba = *(const f32x4*)&lnb[c1*8], bb = *(const f32x4*)&lnb[c1*8+4];
      f32x4 o0, o1;
      #pragma unroll
      for (int j=0;j<4;++j){ o0[j] = (x1[j]-mu)*rs*ga[j]+ba[j]; o1[j] = (x1[4+j]-mu)*rs*gb[j]+bb[j]; }
      __builtin_nontemporal_store(o0, (f32x4*)&outp[(size_t)row*768 + c1*8]);
      __builtin_nontemporal_store(o1, (f32x4*)&outp[(size_t)row*768 + c1*8 + 4]);
    }
    if (lane < 32){
      f32x4 ga = *(const f32x4*)&lng[c2*8], gb = *(const f32x4*)&lng[c2*8+4];
      f32x4 ba = *(const f32x4*)&lnb[c2*8], bb = *(const f32x4*)&lnb[c2*8+4];
      f32x4 o0, o1;
      #pragma unroll
      for (int j=0;j<4;++j){ o0[j] = (x2[j]-mu)*rs*ga[j]+ba[j]; o1[j] = (x2[4+j]-mu)*rs*gb[j]+bb[j]; }
      __builtin_nontemporal_store(o0, (f32x4*)&outp[(size_t)row*768 + c2*8]);
      __builtin_nontemporal_store(o1, (f32x4*)&outp[(size_t)row*768 + c2*8 + 4]);
    }
  }
}

extern "C" void kernel_launch(void* const* d_in, const int* in_sizes, int n_in,
                              void* d_out, int out_size, void* d_ws, size_t ws_size,
                              hipStream_t stream) {
  (void)in_sizes; (void)n_in; (void)out_size; (void)ws_size;
  const float* hs  = (const float*)d_in[0];
  const float* ce  = (const float*)d_in[1];
  const float* Wq  = (const float*)d_in[2];
  const float* bq  = (const float*)d_in[3];
  const float* Wk  = (const float*)d_in[4];
  const float* bk  = (const float*)d_in[5];
  const float* Wv  = (const float*)d_in[6];
  const float* bv  = (const float*)d_in[7];
  const float* Wo  = (const float*)d_in[8];
  const float* bo  = (const float*)d_in[9];
  const float* Wg1 = (const float*)d_in[10];
  const float* bg1 = (const float*)d_in[11];
  const float* Wg2 = (const float*)d_in[12];
  const float* bg2 = (const float*)d_in[13];
  const float* lng = (const float*)d_in[14];
  const float* lnb = (const float*)d_in[15];
  char* ws = (char*)d_ws;
  short* WeffI = (short*)(ws + 0);
  short* VWoI  = (short*)(ws + 1179648);
  short* WaI   = (short*)(ws + 2359296);
  short* WbI   = (short*)(ws + 3538944);
  short* Kc    = (short*)(ws + 4718592);
  short* VT    = (short*)(ws + 4816896);
  float* wg1c  = (float*)(ws + 4915200);
  float* cp    = (float*)(ws + 4918272);
  float* rel   = (float*)(ws + 4970496);
  float* tpp   = (float*)(ws + 4970752);
  float* gpart = (float*)(ws + 4970752);   // aliases tpp (dead by gate_mm); 3*65536*4
  float* sbias = (float*)(ws + 6543616);
  float* outp  = (float*)d_out;

  prep1   <<<168, 256, 0, stream>>>(ce, Wk, bk, Wv, bv, Wg1, Kc, VT, WaI, WbI);
  prep2   <<<113, 256, 0, stream>>>(Wg1, ce, bq, Kc, Wq, Wo, VT, wg1c, cp, sbias, WeffI, VWoI);
  prep_hs <<<512, 384, 0, stream>>>(hs, outp, tpp);
  pool23  <<<16,  256, 0, stream>>>(tpp, cp, rel);
  hipFuncSetAttribute(reinterpret_cast<const void*>(gs256),
                      hipFuncAttributeMaxDynamicSharedMemorySize, 131072);
  gs256   <<<512, 512, 131072, stream>>>(WeffI, sbias, outp);
  gvwo    <<<1024,256, 0, stream>>>(VWoI, bo, outp);
  hipFuncSetAttribute(reinterpret_cast<const void*>(gate_mm),
                      hipFuncAttributeMaxDynamicSharedMemorySize, 131072);
  gate_mm <<<768, 512, 131072, stream>>>(WaI, WbI, bg1, wg1c, Wg2, rel, gpart, outp);
  lnk     <<<2048,256, 0, stream>>>(gpart, bg2, lng, lnb, outp);
}